// Round 6
// baseline (136.809 us; speedup 1.0000x reference)
//
#include <hip/hip_runtime.h>

typedef __attribute__((ext_vector_type(4))) float f32x4;
typedef __attribute__((ext_vector_type(16))) float f32x16;
typedef __attribute__((ext_vector_type(8))) short bf16x8;

__device__ __forceinline__ unsigned short f2bf(float f) {
  union { float f; unsigned u; } v; v.f = f;
  unsigned r = (v.u + 0x7FFFu + ((v.u >> 16) & 1u)) >> 16;
  return (unsigned short)r;
}

__device__ __forceinline__ unsigned cvt_pk_bf16(float lo, float hi) {
  unsigned r;
  asm("v_cvt_pk_bf16_f32 %0, %1, %2" : "=v"(r) : "v"(lo), "v"(hi));
  return r;
}

__device__ __forceinline__ void load16_lds(const void* g, void* l) {
  __builtin_amdgcn_global_load_lds(
      (__attribute__((address_space(1))) void*)(uintptr_t)g,
      (__attribute__((address_space(3))) void*)(unsigned int)(uintptr_t)l,
      16, 0, 0);
}

// log2(e) / sqrt(256)
#define QSCALE 0.09016844f

// ---------- weight fp32 -> bf16 convert; Wq,bq pre-scaled by QSCALE ----------
__global__ __launch_bounds__(256) void convert_w(
    const float* __restrict__ wq, const float* __restrict__ wk,
    const float* __restrict__ wv, const float* __restrict__ wo,
    const float* __restrict__ bq, const float* __restrict__ bk,
    unsigned short* __restrict__ wqkb, unsigned short* __restrict__ wvb,
    unsigned short* __restrict__ wob, float* __restrict__ bqkf) {
  const float* src[4] = {wq, wk, wv, wo};
  unsigned short* dst[4] = {wqkb, wqkb + 65536, wvb, wob};
  int ti = blockIdx.y;
  float sc = (ti == 0) ? QSCALE : 1.f;
  int idx = blockIdx.x * 256 + threadIdx.x;
  float4 v = ((const float4*)src[ti])[idx];
  ushort4 r;
  r.x = f2bf(v.x * sc); r.y = f2bf(v.y * sc);
  r.z = f2bf(v.z * sc); r.w = f2bf(v.w * sc);
  ((ushort4*)dst[ti])[idx] = r;
  if (ti == 3 && blockIdx.x == 0) {
    bqkf[threadIdx.x] = bq[threadIdx.x] * QSCALE;
    bqkf[256 + threadIdx.x] = bk[threadIdx.x];
  }
}

// ---------- GroupNorm: x[b][c][n] f32 -> h_t[b][n][c] bf16 ----------
__global__ __launch_bounds__(256) void gn_kernel(
    const float* __restrict__ x, const float* __restrict__ gamma,
    const float* __restrict__ beta, unsigned short* __restrict__ h) {
  __shared__ float xs[8 * 1024];
  __shared__ float red[16];
  const int t = threadIdx.x;
  const int b = blockIdx.x >> 5, g = blockIdx.x & 31;
  const float* xp = x + (size_t)(b * 256 + g * 8) * 1024;
  float s = 0.f, ss = 0.f;
#pragma unroll
  for (int j = 0; j < 8; ++j) {
    float4 v = ((const float4*)xp)[j * 256 + t];
    ((float4*)xs)[j * 256 + t] = v;
    s += v.x + v.y + v.z + v.w;
    ss += v.x * v.x + v.y * v.y + v.z * v.z + v.w * v.w;
  }
#pragma unroll
  for (int o = 32; o >= 1; o >>= 1) {
    s += __shfl_xor(s, o);
    ss += __shfl_xor(ss, o);
  }
  const int wave = t >> 6, lane = t & 63;
  if (lane == 0) { red[wave] = s; red[wave + 4] = ss; }
  __syncthreads();
  s = red[0] + red[1] + red[2] + red[3];
  ss = red[4] + red[5] + red[6] + red[7];
  float mean = s * (1.f / 8192.f);
  float var = ss * (1.f / 8192.f) - mean * mean;
  float rstd = rsqrtf(var + 1e-5f);
  float a[8], c[8];
#pragma unroll
  for (int ci = 0; ci < 8; ++ci) {
    float gm = gamma[g * 8 + ci], bt = beta[g * 8 + ci];
    a[ci] = rstd * gm;
    c[ci] = bt - mean * rstd * gm;
  }
  unsigned short* hb = h + (size_t)b * 1024 * 256 + g * 8;
#pragma unroll
  for (int j = 0; j < 4; ++j) {
    int n = j * 256 + t;
    float f0 = xs[0 * 1024 + n] * a[0] + c[0];
    float f1 = xs[1 * 1024 + n] * a[1] + c[1];
    float f2 = xs[2 * 1024 + n] * a[2] + c[2];
    float f3 = xs[3 * 1024 + n] * a[3] + c[3];
    float f4 = xs[4 * 1024 + n] * a[4] + c[4];
    float f5 = xs[5 * 1024 + n] * a[5] + c[5];
    float f6 = xs[6 * 1024 + n] * a[6] + c[6];
    float f7 = xs[7 * 1024 + n] * a[7] + c[7];
    uint4 o4;
    o4.x = (unsigned)f2bf(f0) | ((unsigned)f2bf(f1) << 16);
    o4.y = (unsigned)f2bf(f2) | ((unsigned)f2bf(f3) << 16);
    o4.z = (unsigned)f2bf(f4) | ((unsigned)f2bf(f5) << 16);
    o4.w = (unsigned)f2bf(f6) | ((unsigned)f2bf(f7) << 16);
    *(uint4*)(hb + (size_t)n * 256) = o4;
  }
}

// ---------- generic MFMA GEMM: C[M][N] = alpha * A[M][K] * B[N][K]^T ----------
template <bool OUT_F32, int BIAS_MODE, bool HAS_RES>
__global__ __launch_bounds__(256) void gemm_bt(
    const unsigned short* __restrict__ A, long long sAb,
    const unsigned short* __restrict__ Bm, long long sBb,
    void* __restrict__ Cv, long long sCb,
    const float* __restrict__ bias,
    const float* __restrict__ res, long long sRb,
    int M, int N, int K, float alpha) {
  __shared__ unsigned short As[128 * 32];
  __shared__ unsigned short Bs[128 * 32];
  const int t = threadIdx.x;
  const int wave = t >> 6, lane = t & 63;
  const int bm = blockIdx.y * 128, bn = blockIdx.x * 128;
  const int bz = blockIdx.z;
  const unsigned short* Ab = A + (size_t)bz * sAb;
  const unsigned short* Bb = Bm + (size_t)bz * sBb;
  const int wm = (wave >> 1) * 64, wn = (wave & 1) * 64;
  const int srow = t >> 2;
  const int schunk = t & 3;
  const int lrow = lane & 15, kg = lane >> 4;

  f32x4 acc[4][4] = {};

  for (int k0 = 0; k0 < K; k0 += 32) {
#pragma unroll
    for (int r = 0; r < 2; ++r) {
      int row = r * 64 + srow;
      int cs = schunk ^ ((row >> 1) & 3);
      const unsigned short* ga = Ab + (size_t)(bm + row) * K + (k0 + cs * 8);
      const unsigned short* gb = Bb + (size_t)(bn + row) * K + (k0 + cs * 8);
      load16_lds(ga, &As[(r * 64 + wave * 16) * 32]);
      load16_lds(gb, &Bs[(r * 64 + wave * 16) * 32]);
    }
    __syncthreads();
    bf16x8 af[4], bfr[4];
#pragma unroll
    for (int i = 0; i < 4; ++i) {
      int ra = wm + i * 16 + lrow;
      af[i] = *(const bf16x8*)&As[ra * 32 + ((kg ^ ((ra >> 1) & 3)) * 8)];
      int rb = wn + i * 16 + lrow;
      bfr[i] = *(const bf16x8*)&Bs[rb * 32 + ((kg ^ ((rb >> 1) & 3)) * 8)];
    }
#pragma unroll
    for (int i = 0; i < 4; ++i)
#pragma unroll
      for (int j = 0; j < 4; ++j)
        acc[i][j] = __builtin_amdgcn_mfma_f32_16x16x32_bf16(af[i], bfr[j], acc[i][j], 0, 0, 0);
    __syncthreads();
  }

#pragma unroll
  for (int i = 0; i < 4; ++i) {
#pragma unroll
    for (int j = 0; j < 4; ++j) {
#pragma unroll
      for (int r = 0; r < 4; ++r) {
        int m = bm + wm + i * 16 + (lane >> 4) * 4 + r;
        int n = bn + wn + j * 16 + lrow;
        float v = acc[i][j][r] * alpha;
        if constexpr (BIAS_MODE == 1) v += bias[m];
        if constexpr (BIAS_MODE == 2) v += bias[n];
        if constexpr (HAS_RES) v += res[(size_t)bz * sRb + (size_t)m * N + n];
        if constexpr (OUT_F32)
          ((float*)Cv)[(size_t)bz * sCb + (size_t)m * N + n] = v;
        else
          ((unsigned short*)Cv)[(size_t)bz * sCb + (size_t)m * N + n] = f2bf(v);
      }
    }
  }
}

// ---------- fused flash attention v4: 32x32 MFMA, in-register P ----------
// qk: [32][1024][512] (q cols 0-255 pre-scaled by QSCALE, k cols 256-511)
// vt: [32][256][1024]; ot: [32][1024][256]
// 8 waves = 4 q-groups (wr) x 2 kv-halves (wh). Wave tile: 32q x 32kv, full 256c.
// K dbuf 2x32KB + V tbuf 3x32KB = 160KB. PV lags QK by one tile (P in regs).
__global__ __launch_bounds__(512, 2) void flash_attn(
    const unsigned short* __restrict__ qk,
    const unsigned short* __restrict__ vt,
    unsigned short* __restrict__ ot) {
  __shared__ unsigned short SMEM[81920];  // 160 KiB

  const int t = threadIdx.x;
  const int wave = t >> 6, lane = t & 63;
  const int wr = wave & 3, wh = wave >> 2;
  const int l31 = lane & 31, h = lane >> 5;

  const int lbid = blockIdx.x;
  const int logical = (lbid & 7) * 32 + (lbid >> 3);
  const int b = logical >> 3;
  const int q0 = (logical & 7) * 128;

  const unsigned short* qb = qk + (size_t)b * 1024 * 512;
  const unsigned short* kb = qb + 256;
  const unsigned short* vb = vt + (size_t)b * 1024 * 256;

  auto stageK = [&](int T, int buf) {
#pragma unroll
    for (int p = 0; p < 4; ++p) {
      int row = p * 16 + wave * 2 + h;
      int ch = l31 ^ (row & 31);
      load16_lds(kb + (size_t)(T * 64 + row) * 512 + ch * 8,
                 &SMEM[buf * 16384 + (p * 16 + wave * 2) * 256]);
    }
  };
  auto stageV = [&](int T, int buf) {
#pragma unroll
    for (int p = 0; p < 4; ++p) {
      int c = p * 64 + wave * 8 + (lane >> 3);
      int ch = (lane & 7) ^ (c & 7);
      load16_lds(vb + (size_t)c * 1024 + T * 64 + ch * 8,
                 &SMEM[32768 + buf * 16384 + (p * 64 + wave * 8) * 64]);
    }
  };

  // prologue: stage tile 0
  stageK(0, 0);
  stageV(0, 0);

  // Q resident: B-fragments, row q = lane&31 (within wave's 32 rows)
  bf16x8 aq[16];
#pragma unroll
  for (int kk = 0; kk < 16; ++kk)
    aq[kk] = *(const bf16x8*)(qb + (size_t)(q0 + wr * 32 + l31) * 512 + kk * 16 + h * 8);

  f32x16 acco[8] = {};
  float lsum = 0.f;
  unsigned pw[8];

  asm volatile("s_waitcnt vmcnt(0)" ::: "memory");
  __builtin_amdgcn_s_barrier();
  __builtin_amdgcn_sched_barrier(0);

  for (int tt = 0; tt <= 16; ++tt) {
    const int cur = tt & 1;

    // stage K(tt+1) -> KB[cur^1], V(tt+1) -> VB[(tt+1)%3]
    if (tt < 15) {
      stageK(tt + 1, cur ^ 1);
      stageV(tt + 1, (tt + 1) % 3);
    }

    // QK(tt): S^T = K . Q^T (swapped). D: col=lane&31=q, rows=kv.
    f32x16 accs = {};
    if (tt < 16) {
      const int kbase = cur * 16384;
      const int krow = (wh * 32 + l31) * 256;
#pragma unroll
      for (int kk = 0; kk < 16; ++kk) {
        bf16x8 kf = *(const bf16x8*)&SMEM[kbase + krow + (((kk * 2 + h) ^ l31) << 3)];
        accs = __builtin_amdgcn_mfma_f32_32x32x16_bf16(kf, aq[kk], accs, 0, 0, 0);
      }
    }

    // PV(tt-1): O += P . V^T, P from regs (pw), V from VB[(tt-1)%3]
    if (tt >= 1) {
      const int vbase = 32768 + ((tt - 1) % 3) * 16384;
      union { unsigned u[4]; bf16x8 v; } pa, pb;
      pa.u[0] = pw[0]; pa.u[1] = pw[1]; pa.u[2] = pw[2]; pa.u[3] = pw[3];
      pb.u[0] = pw[4]; pb.u[1] = pw[5]; pb.u[2] = pw[6]; pb.u[3] = pw[7];
      const int vx = l31 & 7;
#pragma unroll
      for (int ct = 0; ct < 8; ++ct) {
        const int vrow = vbase + (ct * 32 + l31) * 64;
        bf16x8 vf0 = *(const bf16x8*)&SMEM[vrow + (((wh * 4 + h) ^ vx) << 3)];
        acco[ct] = __builtin_amdgcn_mfma_f32_32x32x16_bf16(pa.v, vf0, acco[ct], 0, 0, 0);
        bf16x8 vf1 = *(const bf16x8*)&SMEM[vrow + (((wh * 4 + 2 + h) ^ vx) << 3)];
        acco[ct] = __builtin_amdgcn_mfma_f32_32x32x16_bf16(pb.v, vf1, acco[ct], 0, 0, 0);
      }
    }

    // exp(tt) -> P bf16 A-fragments in registers (cvt_pk + permlane32_swap)
    if (tt < 16) {
      f32x16 pr;
#pragma unroll
      for (int r = 0; r < 16; ++r) {
        pr[r] = __builtin_amdgcn_exp2f(accs[r]);
        lsum += pr[r];
      }
      unsigned a0 = cvt_pk_bf16(pr[0], pr[1]), a1 = cvt_pk_bf16(pr[2], pr[3]);
      unsigned a2 = cvt_pk_bf16(pr[4], pr[5]), a3 = cvt_pk_bf16(pr[6], pr[7]);
      asm volatile("v_permlane32_swap_b32 %0, %1" : "+v"(a0), "+v"(a2));
      asm volatile("v_permlane32_swap_b32 %0, %1" : "+v"(a1), "+v"(a3));
      pw[0] = a0; pw[1] = a1; pw[2] = a2; pw[3] = a3;
      unsigned b0 = cvt_pk_bf16(pr[8], pr[9]), b1 = cvt_pk_bf16(pr[10], pr[11]);
      unsigned b2 = cvt_pk_bf16(pr[12], pr[13]), b3 = cvt_pk_bf16(pr[14], pr[15]);
      asm volatile("v_permlane32_swap_b32 %0, %1" : "+v"(b0), "+v"(b2));
      asm volatile("v_permlane32_swap_b32 %0, %1" : "+v"(b1), "+v"(b3));
      pw[4] = b0; pw[5] = b1; pw[6] = b2; pw[7] = b3;
    }

    asm volatile("s_waitcnt vmcnt(0) lgkmcnt(0)" ::: "memory");
    __builtin_amdgcn_s_barrier();
    __builtin_amdgcn_sched_barrier(0);
  }

  // ---- epilogue ----
  // lsum: lane l and l^32 cover same q=lane&31 (different kv rows)
  lsum += __shfl_xor(lsum, 32);
  float* lred = (float*)SMEM;
  if (lane < 32) lred[wave * 32 + lane] = lsum;
  __syncthreads();
  float ltot = lsum + lred[(wave ^ 4) * 32 + l31];
  __syncthreads();

  // cross-wh O combine: wh0 sends ct4-7 (region 0), wh1 sends ct0-3 (region 1)
  float* ex = (float*)SMEM;
  if (wh == 0) {
#pragma unroll
    for (int ctl = 0; ctl < 4; ++ctl)
#pragma unroll
      for (int r = 0; r < 16; ++r)
        ex[((wr * 4 + ctl) * 16 + r) * 64 + lane] = acco[4 + ctl][r];
  } else {
#pragma unroll
    for (int ctl = 0; ctl < 4; ++ctl)
#pragma unroll
      for (int r = 0; r < 16; ++r)
        ex[16384 + ((wr * 4 + ctl) * 16 + r) * 64 + lane] = acco[ctl][r];
  }
  __syncthreads();

  float linv[16];
#pragma unroll
  for (int r = 0; r < 16; ++r) {
    int q = (r & 3) + 8 * (r >> 2) + 4 * h;
    linv[r] = 1.f / __shfl(ltot, q);
  }

  unsigned short* ob = ot + (size_t)b * 1024 * 256;
  if (wh == 0) {
#pragma unroll
    for (int ctl = 0; ctl < 4; ++ctl) {
#pragma unroll
      for (int r = 0; r < 16; ++r) {
        float o = (acco[ctl][r] + ex[16384 + ((wr * 4 + ctl) * 16 + r) * 64 + lane]) * linv[r];
        int q = (r & 3) + 8 * (r >> 2) + 4 * h;
        ob[(size_t)(q0 + wr * 32 + q) * 256 + ctl * 32 + l31] = f2bf(o);
      }
    }
  } else {
#pragma unroll
    for (int ctl = 0; ctl < 4; ++ctl) {
#pragma unroll
      for (int r = 0; r < 16; ++r) {
        float o = (acco[4 + ctl][r] + ex[((wr * 4 + ctl) * 16 + r) * 64 + lane]) * linv[r];
        int q = (r & 3) + 8 * (r >> 2) + 4 * h;
        ob[(size_t)(q0 + wr * 32 + q) * 256 + (4 + ctl) * 32 + l31] = f2bf(o);
      }
    }
  }
}

extern "C" void kernel_launch(void* const* d_in, const int* in_sizes, int n_in,
                              void* d_out, int out_size, void* d_ws, size_t ws_size,
                              hipStream_t stream) {
  const float* x    = (const float*)d_in[0];
  const float* gnsc = (const float*)d_in[1];
  const float* gnb  = (const float*)d_in[2];
  const float* wq   = (const float*)d_in[3];
  const float* bq   = (const float*)d_in[4];
  const float* wk   = (const float*)d_in[5];
  const float* bk   = (const float*)d_in[6];
  const float* wv   = (const float*)d_in[7];
  const float* bv   = (const float*)d_in[8];
  const float* wo   = (const float*)d_in[9];
  const float* bo   = (const float*)d_in[10];
  float* out = (float*)d_out;

  unsigned short* wqkb = (unsigned short*)d_ws;          // [512][256]
  unsigned short* wvb  = wqkb + 131072;
  unsigned short* wob  = wvb + 65536;
  float*          bqkf = (float*)(wob + 65536);          // [512] f32
  unsigned short* h    = wob + 65536 + 2048;             // [32][1024][256]
  unsigned short* qkb  = h + 8388608;                    // [32][1024][512]
  unsigned short* vt   = qkb + 16777216;                 // [32][256][1024]
  unsigned short* ot   = h;                              // reuse

  const long long sHN = 1024LL * 256;
  const long long sQK = 1024LL * 512;

  convert_w<<<dim3(64, 4), 256, 0, stream>>>(wq, wk, wv, wo, bq, bk, wqkb, wvb, wob, bqkf);
  gn_kernel<<<dim3(1024), 256, 0, stream>>>(x, gnsc, gnb, h);
  gemm_bt<false, 2, false><<<dim3(4, 8, 32), 256, 0, stream>>>(
      h, sHN, wqkb, 0, qkb, sQK, bqkf, nullptr, 0, 1024, 512, 256, 1.f);
  gemm_bt<false, 1, false><<<dim3(8, 2, 32), 256, 0, stream>>>(
      wvb, 0, h, sHN, vt, sHN, bv, nullptr, 0, 256, 1024, 256, 1.f);
  flash_attn<<<dim3(256), 512, 0, stream>>>(qkb, vt, ot);
  gemm_bt<true, 1, true><<<dim3(8, 2, 32), 256, 0, stream>>>(
      wob, 0, ot, sHN, out, sHN, bo, x, sHN, 256, 1024, 256, 1.f);
}

// Round 7
// 136.776 us; speedup vs baseline: 1.0002x; 1.0002x over previous
//
#include <hip/hip_runtime.h>

typedef __attribute__((ext_vector_type(4))) float f32x4;
typedef __attribute__((ext_vector_type(16))) float f32x16;
typedef __attribute__((ext_vector_type(8))) short bf16x8;

__device__ __forceinline__ unsigned short f2bf(float f) {
  union { float f; unsigned u; } v; v.f = f;
  unsigned r = (v.u + 0x7FFFu + ((v.u >> 16) & 1u)) >> 16;
  return (unsigned short)r;
}

__device__ __forceinline__ unsigned cvt_pk_bf16(float lo, float hi) {
  unsigned r;
  asm("v_cvt_pk_bf16_f32 %0, %1, %2" : "=v"(r) : "v"(lo), "v"(hi));
  return r;
}

__device__ __forceinline__ void load16_lds(const void* g, void* l) {
  __builtin_amdgcn_global_load_lds(
      (__attribute__((address_space(1))) void*)(uintptr_t)g,
      (__attribute__((address_space(3))) void*)(unsigned int)(uintptr_t)l,
      16, 0, 0);
}

// log2(e) / sqrt(256)
#define QSCALE 0.09016844f

// ---------- weight fp32 -> bf16 convert; Wq,bq pre-scaled by QSCALE ----------
__global__ __launch_bounds__(256) void convert_w(
    const float* __restrict__ wq, const float* __restrict__ wk,
    const float* __restrict__ wv, const float* __restrict__ wo,
    const float* __restrict__ bq, const float* __restrict__ bk,
    unsigned short* __restrict__ wqkb, unsigned short* __restrict__ wvb,
    unsigned short* __restrict__ wob, float* __restrict__ bqkf) {
  const float* src[4] = {wq, wk, wv, wo};
  unsigned short* dst[4] = {wqkb, wqkb + 65536, wvb, wob};
  int ti = blockIdx.y;
  float sc = (ti == 0) ? QSCALE : 1.f;
  int idx = blockIdx.x * 256 + threadIdx.x;
  float4 v = ((const float4*)src[ti])[idx];
  ushort4 r;
  r.x = f2bf(v.x * sc); r.y = f2bf(v.y * sc);
  r.z = f2bf(v.z * sc); r.w = f2bf(v.w * sc);
  ((ushort4*)dst[ti])[idx] = r;
  if (ti == 3 && blockIdx.x == 0) {
    bqkf[threadIdx.x] = bq[threadIdx.x] * QSCALE;
    bqkf[256 + threadIdx.x] = bk[threadIdx.x];
  }
}

// ---------- GroupNorm: x[b][c][n] f32 -> h_t[b][n][c] bf16 ----------
__global__ __launch_bounds__(256) void gn_kernel(
    const float* __restrict__ x, const float* __restrict__ gamma,
    const float* __restrict__ beta, unsigned short* __restrict__ h) {
  __shared__ float xs[8 * 1024];
  __shared__ float red[16];
  const int t = threadIdx.x;
  const int b = blockIdx.x >> 5, g = blockIdx.x & 31;
  const float* xp = x + (size_t)(b * 256 + g * 8) * 1024;
  float s = 0.f, ss = 0.f;
#pragma unroll
  for (int j = 0; j < 8; ++j) {
    float4 v = ((const float4*)xp)[j * 256 + t];
    ((float4*)xs)[j * 256 + t] = v;
    s += v.x + v.y + v.z + v.w;
    ss += v.x * v.x + v.y * v.y + v.z * v.z + v.w * v.w;
  }
#pragma unroll
  for (int o = 32; o >= 1; o >>= 1) {
    s += __shfl_xor(s, o);
    ss += __shfl_xor(ss, o);
  }
  const int wave = t >> 6, lane = t & 63;
  if (lane == 0) { red[wave] = s; red[wave + 4] = ss; }
  __syncthreads();
  s = red[0] + red[1] + red[2] + red[3];
  ss = red[4] + red[5] + red[6] + red[7];
  float mean = s * (1.f / 8192.f);
  float var = ss * (1.f / 8192.f) - mean * mean;
  float rstd = rsqrtf(var + 1e-5f);
  float a[8], c[8];
#pragma unroll
  for (int ci = 0; ci < 8; ++ci) {
    float gm = gamma[g * 8 + ci], bt = beta[g * 8 + ci];
    a[ci] = rstd * gm;
    c[ci] = bt - mean * rstd * gm;
  }
  unsigned short* hb = h + (size_t)b * 1024 * 256 + g * 8;
#pragma unroll
  for (int j = 0; j < 4; ++j) {
    int n = j * 256 + t;
    float f0 = xs[0 * 1024 + n] * a[0] + c[0];
    float f1 = xs[1 * 1024 + n] * a[1] + c[1];
    float f2 = xs[2 * 1024 + n] * a[2] + c[2];
    float f3 = xs[3 * 1024 + n] * a[3] + c[3];
    float f4 = xs[4 * 1024 + n] * a[4] + c[4];
    float f5 = xs[5 * 1024 + n] * a[5] + c[5];
    float f6 = xs[6 * 1024 + n] * a[6] + c[6];
    float f7 = xs[7 * 1024 + n] * a[7] + c[7];
    uint4 o4;
    o4.x = (unsigned)f2bf(f0) | ((unsigned)f2bf(f1) << 16);
    o4.y = (unsigned)f2bf(f2) | ((unsigned)f2bf(f3) << 16);
    o4.z = (unsigned)f2bf(f4) | ((unsigned)f2bf(f5) << 16);
    o4.w = (unsigned)f2bf(f6) | ((unsigned)f2bf(f7) << 16);
    *(uint4*)(hb + (size_t)n * 256) = o4;
  }
}

// ---------- generic MFMA GEMM: C[M][N] = alpha * A[M][K] * B[N][K]^T ----------
template <bool OUT_F32, int BIAS_MODE, bool HAS_RES>
__global__ __launch_bounds__(256) void gemm_bt(
    const unsigned short* __restrict__ A, long long sAb,
    const unsigned short* __restrict__ Bm, long long sBb,
    void* __restrict__ Cv, long long sCb,
    const float* __restrict__ bias,
    const float* __restrict__ res, long long sRb,
    int M, int N, int K, float alpha) {
  __shared__ unsigned short As[128 * 32];
  __shared__ unsigned short Bs[128 * 32];
  const int t = threadIdx.x;
  const int wave = t >> 6, lane = t & 63;
  const int bm = blockIdx.y * 128, bn = blockIdx.x * 128;
  const int bz = blockIdx.z;
  const unsigned short* Ab = A + (size_t)bz * sAb;
  const unsigned short* Bb = Bm + (size_t)bz * sBb;
  const int wm = (wave >> 1) * 64, wn = (wave & 1) * 64;
  const int srow = t >> 2;
  const int schunk = t & 3;
  const int lrow = lane & 15, kg = lane >> 4;

  f32x4 acc[4][4] = {};

  for (int k0 = 0; k0 < K; k0 += 32) {
#pragma unroll
    for (int r = 0; r < 2; ++r) {
      int row = r * 64 + srow;
      int cs = schunk ^ ((row >> 1) & 3);
      const unsigned short* ga = Ab + (size_t)(bm + row) * K + (k0 + cs * 8);
      const unsigned short* gb = Bb + (size_t)(bn + row) * K + (k0 + cs * 8);
      load16_lds(ga, &As[(r * 64 + wave * 16) * 32]);
      load16_lds(gb, &Bs[(r * 64 + wave * 16) * 32]);
    }
    __syncthreads();
    bf16x8 af[4], bfr[4];
#pragma unroll
    for (int i = 0; i < 4; ++i) {
      int ra = wm + i * 16 + lrow;
      af[i] = *(const bf16x8*)&As[ra * 32 + ((kg ^ ((ra >> 1) & 3)) * 8)];
      int rb = wn + i * 16 + lrow;
      bfr[i] = *(const bf16x8*)&Bs[rb * 32 + ((kg ^ ((rb >> 1) & 3)) * 8)];
    }
#pragma unroll
    for (int i = 0; i < 4; ++i)
#pragma unroll
      for (int j = 0; j < 4; ++j)
        acc[i][j] = __builtin_amdgcn_mfma_f32_16x16x32_bf16(af[i], bfr[j], acc[i][j], 0, 0, 0);
    __syncthreads();
  }

#pragma unroll
  for (int i = 0; i < 4; ++i) {
#pragma unroll
    for (int j = 0; j < 4; ++j) {
#pragma unroll
      for (int r = 0; r < 4; ++r) {
        int m = bm + wm + i * 16 + (lane >> 4) * 4 + r;
        int n = bn + wn + j * 16 + lrow;
        float v = acc[i][j][r] * alpha;
        if constexpr (BIAS_MODE == 1) v += bias[m];
        if constexpr (BIAS_MODE == 2) v += bias[n];
        if constexpr (HAS_RES) v += res[(size_t)bz * sRb + (size_t)m * N + n];
        if constexpr (OUT_F32)
          ((float*)Cv)[(size_t)bz * sCb + (size_t)m * N + n] = v;
        else
          ((unsigned short*)Cv)[(size_t)bz * sCb + (size_t)m * N + n] = f2bf(v);
      }
    }
  }
}

// ---------- fused flash attention v4: 32x32 MFMA, in-register P ----------
// qk: [32][1024][512] (q cols 0-255 pre-scaled by QSCALE, k cols 256-511)
// vt: [32][256][1024]; ot: [32][1024][256]
// 8 waves = 4 q-groups (wr) x 2 kv-halves (wh). Wave tile: 32q x 32kv, full 256c.
// K dbuf 2x32KB + V tbuf 3x32KB = 160KB. PV lags QK by one tile (P in regs).
__global__ __launch_bounds__(512, 2) void flash_attn(
    const unsigned short* __restrict__ qk,
    const unsigned short* __restrict__ vt,
    unsigned short* __restrict__ ot) {
  __shared__ unsigned short SMEM[81920];  // 160 KiB

  const int t = threadIdx.x;
  const int wave = t >> 6, lane = t & 63;
  const int wr = wave & 3, wh = wave >> 2;
  const int l31 = lane & 31, h = lane >> 5;

  const int lbid = blockIdx.x;
  const int logical = (lbid & 7) * 32 + (lbid >> 3);
  const int b = logical >> 3;
  const int q0 = (logical & 7) * 128;

  const unsigned short* qb = qk + (size_t)b * 1024 * 512;
  const unsigned short* kb = qb + 256;
  const unsigned short* vb = vt + (size_t)b * 1024 * 256;

  auto stageK = [&](int T, int buf) {
#pragma unroll
    for (int p = 0; p < 4; ++p) {
      int row = p * 16 + wave * 2 + h;
      int ch = l31 ^ (row & 31);
      load16_lds(kb + (size_t)(T * 64 + row) * 512 + ch * 8,
                 &SMEM[buf * 16384 + (p * 16 + wave * 2) * 256]);
    }
  };
  auto stageV = [&](int T, int buf) {
#pragma unroll
    for (int p = 0; p < 4; ++p) {
      int c = p * 64 + wave * 8 + (lane >> 3);
      int ch = (lane & 7) ^ (c & 7);
      load16_lds(vb + (size_t)c * 1024 + T * 64 + ch * 8,
                 &SMEM[32768 + buf * 16384 + (p * 64 + wave * 8) * 64]);
    }
  };

  // prologue: stage tile 0
  stageK(0, 0);
  stageV(0, 0);

  // Q resident: B-fragments, row q = lane&31 (within wave's 32 rows)
  bf16x8 aq[16];
#pragma unroll
  for (int kk = 0; kk < 16; ++kk)
    aq[kk] = *(const bf16x8*)(qb + (size_t)(q0 + wr * 32 + l31) * 512 + kk * 16 + h * 8);

  f32x16 acco[8] = {};
  float lsum = 0.f;
  unsigned pw[8];

  asm volatile("s_waitcnt vmcnt(0)" ::: "memory");
  __builtin_amdgcn_s_barrier();
  __builtin_amdgcn_sched_barrier(0);

  for (int tt = 0; tt <= 16; ++tt) {
    const int cur = tt & 1;

    // stage K(tt+1) -> KB[cur^1], V(tt+1) -> VB[(tt+1)%3]
    if (tt < 15) {
      stageK(tt + 1, cur ^ 1);
      stageV(tt + 1, (tt + 1) % 3);
    }

    // QK(tt): S^T = K . Q^T (swapped). D: col=lane&31=q, rows=kv.
    f32x16 accs = {};
    if (tt < 16) {
      const int kbase = cur * 16384;
      const int krow = (wh * 32 + l31) * 256;
#pragma unroll
      for (int kk = 0; kk < 16; ++kk) {
        bf16x8 kf = *(const bf16x8*)&SMEM[kbase + krow + (((kk * 2 + h) ^ l31) << 3)];
        accs = __builtin_amdgcn_mfma_f32_32x32x16_bf16(kf, aq[kk], accs, 0, 0, 0);
      }
    }

    // PV(tt-1): O += P . V^T, P from regs (pw), V from VB[(tt-1)%3]
    if (tt >= 1) {
      const int vbase = 32768 + ((tt - 1) % 3) * 16384;
      union { unsigned u[4]; bf16x8 v; } pa, pb;
      pa.u[0] = pw[0]; pa.u[1] = pw[1]; pa.u[2] = pw[2]; pa.u[3] = pw[3];
      pb.u[0] = pw[4]; pb.u[1] = pw[5]; pb.u[2] = pw[6]; pb.u[3] = pw[7];
      const int vx = l31 & 7;
#pragma unroll
      for (int ct = 0; ct < 8; ++ct) {
        const int vrow = vbase + (ct * 32 + l31) * 64;
        bf16x8 vf0 = *(const bf16x8*)&SMEM[vrow + (((wh * 4 + h) ^ vx) << 3)];
        acco[ct] = __builtin_amdgcn_mfma_f32_32x32x16_bf16(pa.v, vf0, acco[ct], 0, 0, 0);
        bf16x8 vf1 = *(const bf16x8*)&SMEM[vrow + (((wh * 4 + 2 + h) ^ vx) << 3)];
        acco[ct] = __builtin_amdgcn_mfma_f32_32x32x16_bf16(pb.v, vf1, acco[ct], 0, 0, 0);
      }
    }

    // exp(tt) -> P bf16 A-fragments in registers (cvt_pk + permlane32_swap)
    if (tt < 16) {
      f32x16 pr;
#pragma unroll
      for (int r = 0; r < 16; ++r) {
        pr[r] = __builtin_amdgcn_exp2f(accs[r]);
        lsum += pr[r];
      }
      unsigned a0 = cvt_pk_bf16(pr[0], pr[1]), a1 = cvt_pk_bf16(pr[2], pr[3]);
      unsigned a2 = cvt_pk_bf16(pr[4], pr[5]), a3 = cvt_pk_bf16(pr[6], pr[7]);
      asm volatile("v_permlane32_swap_b32 %0, %1" : "+v"(a0), "+v"(a2));
      asm volatile("v_permlane32_swap_b32 %0, %1" : "+v"(a1), "+v"(a3));
      pw[0] = a0; pw[1] = a1; pw[2] = a2; pw[3] = a3;
      unsigned b0 = cvt_pk_bf16(pr[8], pr[9]), b1 = cvt_pk_bf16(pr[10], pr[11]);
      unsigned b2 = cvt_pk_bf16(pr[12], pr[13]), b3 = cvt_pk_bf16(pr[14], pr[15]);
      asm volatile("v_permlane32_swap_b32 %0, %1" : "+v"(b0), "+v"(b2));
      asm volatile("v_permlane32_swap_b32 %0, %1" : "+v"(b1), "+v"(b3));
      pw[4] = b0; pw[5] = b1; pw[6] = b2; pw[7] = b3;
    }

    asm volatile("s_waitcnt vmcnt(0) lgkmcnt(0)" ::: "memory");
    __builtin_amdgcn_s_barrier();
    __builtin_amdgcn_sched_barrier(0);
  }

  // ---- epilogue ----
  // lsum: lane l and l^32 cover same q=lane&31 (different kv rows)
  lsum += __shfl_xor(lsum, 32);
  float* lred = (float*)SMEM;
  if (lane < 32) lred[wave * 32 + lane] = lsum;
  __syncthreads();
  float ltot = lsum + lred[(wave ^ 4) * 32 + l31];
  __syncthreads();

  // cross-wh O combine: wh0 sends ct4-7 (region 0), wh1 sends ct0-3 (region 1)
  float* ex = (float*)SMEM;
  if (wh == 0) {
#pragma unroll
    for (int ctl = 0; ctl < 4; ++ctl)
#pragma unroll
      for (int r = 0; r < 16; ++r)
        ex[((wr * 4 + ctl) * 16 + r) * 64 + lane] = acco[4 + ctl][r];
  } else {
#pragma unroll
    for (int ctl = 0; ctl < 4; ++ctl)
#pragma unroll
      for (int r = 0; r < 16; ++r)
        ex[16384 + ((wr * 4 + ctl) * 16 + r) * 64 + lane] = acco[ctl][r];
  }
  __syncthreads();

  float linv[16];
#pragma unroll
  for (int r = 0; r < 16; ++r) {
    int q = (r & 3) + 8 * (r >> 2) + 4 * h;
    linv[r] = 1.f / __shfl(ltot, q);
  }

  unsigned short* ob = ot + (size_t)b * 1024 * 256;
  if (wh == 0) {
#pragma unroll
    for (int ctl = 0; ctl < 4; ++ctl) {
#pragma unroll
      for (int r = 0; r < 16; ++r) {
        float o = (acco[ctl][r] + ex[16384 + ((wr * 4 + ctl) * 16 + r) * 64 + lane]) * linv[r];
        int q = (r & 3) + 8 * (r >> 2) + 4 * h;
        ob[(size_t)(q0 + wr * 32 + q) * 256 + ctl * 32 + l31] = f2bf(o);
      }
    }
  } else {
#pragma unroll
    for (int ctl = 0; ctl < 4; ++ctl) {
#pragma unroll
      for (int r = 0; r < 16; ++r) {
        float o = (acco[4 + ctl][r] + ex[((wr * 4 + ctl) * 16 + r) * 64 + lane]) * linv[r];
        int q = (r & 3) + 8 * (r >> 2) + 4 * h;
        ob[(size_t)(q0 + wr * 32 + q) * 256 + (4 + ctl) * 32 + l31] = f2bf(o);
      }
    }
  }
}

extern "C" void kernel_launch(void* const* d_in, const int* in_sizes, int n_in,
                              void* d_out, int out_size, void* d_ws, size_t ws_size,
                              hipStream_t stream) {
  const float* x    = (const float*)d_in[0];
  const float* gnsc = (const float*)d_in[1];
  const float* gnb  = (const float*)d_in[2];
  const float* wq   = (const float*)d_in[3];
  const float* bq   = (const float*)d_in[4];
  const float* wk   = (const float*)d_in[5];
  const float* bk   = (const float*)d_in[6];
  const float* wv   = (const float*)d_in[7];
  const float* bv   = (const float*)d_in[8];
  const float* wo   = (const float*)d_in[9];
  const float* bo   = (const float*)d_in[10];
  float* out = (float*)d_out;

  unsigned short* wqkb = (unsigned short*)d_ws;          // [512][256]
  unsigned short* wvb  = wqkb + 131072;
  unsigned short* wob  = wvb + 65536;
  float*          bqkf = (float*)(wob + 65536);          // [512] f32
  unsigned short* h    = wob + 65536 + 2048;             // [32][1024][256]
  unsigned short* qkb  = h + 8388608;                    // [32][1024][512]
  unsigned short* vt   = qkb + 16777216;                 // [32][256][1024]
  unsigned short* ot   = h;                              // reuse

  const long long sHN = 1024LL * 256;
  const long long sQK = 1024LL * 512;

  convert_w<<<dim3(64, 4), 256, 0, stream>>>(wq, wk, wv, wo, bq, bk, wqkb, wvb, wob, bqkf);
  gn_kernel<<<dim3(1024), 256, 0, stream>>>(x, gnsc, gnb, h);
  gemm_bt<false, 2, false><<<dim3(4, 8, 32), 256, 0, stream>>>(
      h, sHN, wqkb, 0, qkb, sQK, bqkf, nullptr, 0, 1024, 512, 256, 1.f);
  gemm_bt<false, 1, false><<<dim3(8, 2, 32), 256, 0, stream>>>(
      wvb, 0, h, sHN, vt, sHN, bv, nullptr, 0, 256, 1024, 256, 1.f);
  flash_attn<<<dim3(256), 512, 0, stream>>>(qkb, vt, ot);
  gemm_bt<true, 1, true><<<dim3(8, 2, 32), 256, 0, stream>>>(
      wob, 0, ot, sHN, out, sHN, bo, x, sHN, 256, 1024, 256, 1.f);
}

// Round 8
// 136.628 us; speedup vs baseline: 1.0013x; 1.0011x over previous
//
#include <hip/hip_runtime.h>

typedef __attribute__((ext_vector_type(4))) float f32x4;
typedef __attribute__((ext_vector_type(16))) float f32x16;
typedef __attribute__((ext_vector_type(8))) short bf16x8;

__device__ __forceinline__ unsigned short f2bf(float f) {
  union { float f; unsigned u; } v; v.f = f;
  unsigned r = (v.u + 0x7FFFu + ((v.u >> 16) & 1u)) >> 16;
  return (unsigned short)r;
}

__device__ __forceinline__ unsigned cvt_pk_bf16(float lo, float hi) {
  unsigned r;
  asm("v_cvt_pk_bf16_f32 %0, %1, %2" : "=v"(r) : "v"(lo), "v"(hi));
  return r;
}

__device__ __forceinline__ void load16_lds(const void* g, void* l) {
  __builtin_amdgcn_global_load_lds(
      (__attribute__((address_space(1))) void*)(uintptr_t)g,
      (__attribute__((address_space(3))) void*)(unsigned int)(uintptr_t)l,
      16, 0, 0);
}

// log2(e) / sqrt(256)
#define QSCALE 0.09016844f

// ---------- weight fp32 -> bf16 convert; Wq,bq pre-scaled by QSCALE ----------
__global__ __launch_bounds__(256) void convert_w(
    const float* __restrict__ wq, const float* __restrict__ wk,
    const float* __restrict__ wv, const float* __restrict__ wo,
    const float* __restrict__ bq, const float* __restrict__ bk,
    unsigned short* __restrict__ wqkb, unsigned short* __restrict__ wvb,
    unsigned short* __restrict__ wob, float* __restrict__ bqkf) {
  const float* src[4] = {wq, wk, wv, wo};
  unsigned short* dst[4] = {wqkb, wqkb + 65536, wvb, wob};
  int ti = blockIdx.y;
  float sc = (ti == 0) ? QSCALE : 1.f;
  int idx = blockIdx.x * 256 + threadIdx.x;
  float4 v = ((const float4*)src[ti])[idx];
  ushort4 r;
  r.x = f2bf(v.x * sc); r.y = f2bf(v.y * sc);
  r.z = f2bf(v.z * sc); r.w = f2bf(v.w * sc);
  ((ushort4*)dst[ti])[idx] = r;
  if (ti == 3 && blockIdx.x == 0) {
    bqkf[threadIdx.x] = bq[threadIdx.x] * QSCALE;
    bqkf[256 + threadIdx.x] = bk[threadIdx.x];
  }
}

// ---------- GroupNorm: x[b][c][n] f32 -> h_t[b][n][c] bf16 ----------
__global__ __launch_bounds__(256) void gn_kernel(
    const float* __restrict__ x, const float* __restrict__ gamma,
    const float* __restrict__ beta, unsigned short* __restrict__ h) {
  __shared__ float xs[8 * 1024];
  __shared__ float red[16];
  const int t = threadIdx.x;
  const int b = blockIdx.x >> 5, g = blockIdx.x & 31;
  const float* xp = x + (size_t)(b * 256 + g * 8) * 1024;
  float s = 0.f, ss = 0.f;
#pragma unroll
  for (int j = 0; j < 8; ++j) {
    float4 v = ((const float4*)xp)[j * 256 + t];
    ((float4*)xs)[j * 256 + t] = v;
    s += v.x + v.y + v.z + v.w;
    ss += v.x * v.x + v.y * v.y + v.z * v.z + v.w * v.w;
  }
#pragma unroll
  for (int o = 32; o >= 1; o >>= 1) {
    s += __shfl_xor(s, o);
    ss += __shfl_xor(ss, o);
  }
  const int wave = t >> 6, lane = t & 63;
  if (lane == 0) { red[wave] = s; red[wave + 4] = ss; }
  __syncthreads();
  s = red[0] + red[1] + red[2] + red[3];
  ss = red[4] + red[5] + red[6] + red[7];
  float mean = s * (1.f / 8192.f);
  float var = ss * (1.f / 8192.f) - mean * mean;
  float rstd = rsqrtf(var + 1e-5f);
  float a[8], c[8];
#pragma unroll
  for (int ci = 0; ci < 8; ++ci) {
    float gm = gamma[g * 8 + ci], bt = beta[g * 8 + ci];
    a[ci] = rstd * gm;
    c[ci] = bt - mean * rstd * gm;
  }
  unsigned short* hb = h + (size_t)b * 1024 * 256 + g * 8;
#pragma unroll
  for (int j = 0; j < 4; ++j) {
    int n = j * 256 + t;
    float f0 = xs[0 * 1024 + n] * a[0] + c[0];
    float f1 = xs[1 * 1024 + n] * a[1] + c[1];
    float f2 = xs[2 * 1024 + n] * a[2] + c[2];
    float f3 = xs[3 * 1024 + n] * a[3] + c[3];
    float f4 = xs[4 * 1024 + n] * a[4] + c[4];
    float f5 = xs[5 * 1024 + n] * a[5] + c[5];
    float f6 = xs[6 * 1024 + n] * a[6] + c[6];
    float f7 = xs[7 * 1024 + n] * a[7] + c[7];
    uint4 o4;
    o4.x = (unsigned)f2bf(f0) | ((unsigned)f2bf(f1) << 16);
    o4.y = (unsigned)f2bf(f2) | ((unsigned)f2bf(f3) << 16);
    o4.z = (unsigned)f2bf(f4) | ((unsigned)f2bf(f5) << 16);
    o4.w = (unsigned)f2bf(f6) | ((unsigned)f2bf(f7) << 16);
    *(uint4*)(hb + (size_t)n * 256) = o4;
  }
}

// ---------- generic MFMA GEMM: C[M][N] = alpha * A[M][K] * B[N][K]^T ----------
template <bool OUT_F32, int BIAS_MODE, bool HAS_RES>
__global__ __launch_bounds__(256) void gemm_bt(
    const unsigned short* __restrict__ A, long long sAb,
    const unsigned short* __restrict__ Bm, long long sBb,
    void* __restrict__ Cv, long long sCb,
    const float* __restrict__ bias,
    const float* __restrict__ res, long long sRb,
    int M, int N, int K, float alpha) {
  __shared__ unsigned short As[128 * 32];
  __shared__ unsigned short Bs[128 * 32];
  const int t = threadIdx.x;
  const int wave = t >> 6, lane = t & 63;
  const int bm = blockIdx.y * 128, bn = blockIdx.x * 128;
  const int bz = blockIdx.z;
  const unsigned short* Ab = A + (size_t)bz * sAb;
  const unsigned short* Bb = Bm + (size_t)bz * sBb;
  const int wm = (wave >> 1) * 64, wn = (wave & 1) * 64;
  const int srow = t >> 2;
  const int schunk = t & 3;
  const int lrow = lane & 15, kg = lane >> 4;

  f32x4 acc[4][4] = {};

  for (int k0 = 0; k0 < K; k0 += 32) {
#pragma unroll
    for (int r = 0; r < 2; ++r) {
      int row = r * 64 + srow;
      int cs = schunk ^ ((row >> 1) & 3);
      const unsigned short* ga = Ab + (size_t)(bm + row) * K + (k0 + cs * 8);
      const unsigned short* gb = Bb + (size_t)(bn + row) * K + (k0 + cs * 8);
      load16_lds(ga, &As[(r * 64 + wave * 16) * 32]);
      load16_lds(gb, &Bs[(r * 64 + wave * 16) * 32]);
    }
    __syncthreads();
    bf16x8 af[4], bfr[4];
#pragma unroll
    for (int i = 0; i < 4; ++i) {
      int ra = wm + i * 16 + lrow;
      af[i] = *(const bf16x8*)&As[ra * 32 + ((kg ^ ((ra >> 1) & 3)) * 8)];
      int rb = wn + i * 16 + lrow;
      bfr[i] = *(const bf16x8*)&Bs[rb * 32 + ((kg ^ ((rb >> 1) & 3)) * 8)];
    }
#pragma unroll
    for (int i = 0; i < 4; ++i)
#pragma unroll
      for (int j = 0; j < 4; ++j)
        acc[i][j] = __builtin_amdgcn_mfma_f32_16x16x32_bf16(af[i], bfr[j], acc[i][j], 0, 0, 0);
    __syncthreads();
  }

#pragma unroll
  for (int i = 0; i < 4; ++i) {
#pragma unroll
    for (int j = 0; j < 4; ++j) {
#pragma unroll
      for (int r = 0; r < 4; ++r) {
        int m = bm + wm + i * 16 + (lane >> 4) * 4 + r;
        int n = bn + wn + j * 16 + lrow;
        float v = acc[i][j][r] * alpha;
        if constexpr (BIAS_MODE == 1) v += bias[m];
        if constexpr (BIAS_MODE == 2) v += bias[n];
        if constexpr (HAS_RES) v += res[(size_t)bz * sRb + (size_t)m * N + n];
        if constexpr (OUT_F32)
          ((float*)Cv)[(size_t)bz * sCb + (size_t)m * N + n] = v;
        else
          ((unsigned short*)Cv)[(size_t)bz * sCb + (size_t)m * N + n] = f2bf(v);
      }
    }
  }
}

// ---------- fused flash attention v4: 32x32 MFMA, in-register P ----------
// qk: [32][1024][512] (q cols 0-255 pre-scaled by QSCALE, k cols 256-511)
// vt: [32][256][1024]; ot: [32][1024][256]
// 8 waves = 4 q-groups (wr) x 2 kv-halves (wh). Wave tile: 32q x 32kv, full 256c.
// K dbuf 2x32KB + V tbuf 3x32KB = 160KB. PV lags QK by one tile (P in regs).
__global__ __launch_bounds__(512, 2) void flash_attn(
    const unsigned short* __restrict__ qk,
    const unsigned short* __restrict__ vt,
    unsigned short* __restrict__ ot) {
  __shared__ unsigned short SMEM[81920];  // 160 KiB

  const int t = threadIdx.x;
  const int wave = t >> 6, lane = t & 63;
  const int wr = wave & 3, wh = wave >> 2;
  const int l31 = lane & 31, h = lane >> 5;

  const int lbid = blockIdx.x;
  const int logical = (lbid & 7) * 32 + (lbid >> 3);
  const int b = logical >> 3;
  const int q0 = (logical & 7) * 128;

  const unsigned short* qb = qk + (size_t)b * 1024 * 512;
  const unsigned short* kb = qb + 256;
  const unsigned short* vb = vt + (size_t)b * 1024 * 256;

  auto stageK = [&](int T, int buf) {
#pragma unroll
    for (int p = 0; p < 4; ++p) {
      int row = p * 16 + wave * 2 + h;
      int ch = l31 ^ (row & 31);
      load16_lds(kb + (size_t)(T * 64 + row) * 512 + ch * 8,
                 &SMEM[buf * 16384 + (p * 16 + wave * 2) * 256]);
    }
  };
  auto stageV = [&](int T, int buf) {
#pragma unroll
    for (int p = 0; p < 4; ++p) {
      int c = p * 64 + wave * 8 + (lane >> 3);
      int ch = (lane & 7) ^ (c & 7);
      load16_lds(vb + (size_t)c * 1024 + T * 64 + ch * 8,
                 &SMEM[32768 + buf * 16384 + (p * 64 + wave * 8) * 64]);
    }
  };

  // prologue: stage tile 0
  stageK(0, 0);
  stageV(0, 0);

  // Q resident: B-fragments, row q = lane&31 (within wave's 32 rows)
  bf16x8 aq[16];
#pragma unroll
  for (int kk = 0; kk < 16; ++kk)
    aq[kk] = *(const bf16x8*)(qb + (size_t)(q0 + wr * 32 + l31) * 512 + kk * 16 + h * 8);

  f32x16 acco[8] = {};
  float lsum = 0.f;
  unsigned pw[8];

  asm volatile("s_waitcnt vmcnt(0)" ::: "memory");
  __builtin_amdgcn_s_barrier();
  __builtin_amdgcn_sched_barrier(0);

  for (int tt = 0; tt <= 16; ++tt) {
    const int cur = tt & 1;

    // stage K(tt+1) -> KB[cur^1], V(tt+1) -> VB[(tt+1)%3]
    if (tt < 15) {
      stageK(tt + 1, cur ^ 1);
      stageV(tt + 1, (tt + 1) % 3);
    }

    // QK(tt): S^T = K . Q^T (swapped). D: col=lane&31=q, rows=kv.
    f32x16 accs = {};
    if (tt < 16) {
      const int kbase = cur * 16384;
      const int krow = (wh * 32 + l31) * 256;
#pragma unroll
      for (int kk = 0; kk < 16; ++kk) {
        bf16x8 kf = *(const bf16x8*)&SMEM[kbase + krow + (((kk * 2 + h) ^ l31) << 3)];
        accs = __builtin_amdgcn_mfma_f32_32x32x16_bf16(kf, aq[kk], accs, 0, 0, 0);
      }
    }

    // PV(tt-1): O += P . V^T, P from regs (pw), V from VB[(tt-1)%3]
    if (tt >= 1) {
      const int vbase = 32768 + ((tt - 1) % 3) * 16384;
      union { unsigned u[4]; bf16x8 v; } pa, pb;
      pa.u[0] = pw[0]; pa.u[1] = pw[1]; pa.u[2] = pw[2]; pa.u[3] = pw[3];
      pb.u[0] = pw[4]; pb.u[1] = pw[5]; pb.u[2] = pw[6]; pb.u[3] = pw[7];
      const int vx = l31 & 7;
#pragma unroll
      for (int ct = 0; ct < 8; ++ct) {
        const int vrow = vbase + (ct * 32 + l31) * 64;
        bf16x8 vf0 = *(const bf16x8*)&SMEM[vrow + (((wh * 4 + h) ^ vx) << 3)];
        acco[ct] = __builtin_amdgcn_mfma_f32_32x32x16_bf16(pa.v, vf0, acco[ct], 0, 0, 0);
        bf16x8 vf1 = *(const bf16x8*)&SMEM[vrow + (((wh * 4 + 2 + h) ^ vx) << 3)];
        acco[ct] = __builtin_amdgcn_mfma_f32_32x32x16_bf16(pb.v, vf1, acco[ct], 0, 0, 0);
      }
    }

    // exp(tt) -> P bf16 A-fragments in registers (cvt_pk + permlane32_swap)
    if (tt < 16) {
      f32x16 pr;
#pragma unroll
      for (int r = 0; r < 16; ++r) {
        pr[r] = __builtin_amdgcn_exp2f(accs[r]);
        lsum += pr[r];
      }
      unsigned a0 = cvt_pk_bf16(pr[0], pr[1]), a1 = cvt_pk_bf16(pr[2], pr[3]);
      unsigned a2 = cvt_pk_bf16(pr[4], pr[5]), a3 = cvt_pk_bf16(pr[6], pr[7]);
      asm volatile("v_permlane32_swap_b32 %0, %1" : "+v"(a0), "+v"(a2));
      asm volatile("v_permlane32_swap_b32 %0, %1" : "+v"(a1), "+v"(a3));
      pw[0] = a0; pw[1] = a1; pw[2] = a2; pw[3] = a3;
      unsigned b0 = cvt_pk_bf16(pr[8], pr[9]), b1 = cvt_pk_bf16(pr[10], pr[11]);
      unsigned b2 = cvt_pk_bf16(pr[12], pr[13]), b3 = cvt_pk_bf16(pr[14], pr[15]);
      asm volatile("v_permlane32_swap_b32 %0, %1" : "+v"(b0), "+v"(b2));
      asm volatile("v_permlane32_swap_b32 %0, %1" : "+v"(b1), "+v"(b3));
      pw[4] = b0; pw[5] = b1; pw[6] = b2; pw[7] = b3;
    }

    asm volatile("s_waitcnt vmcnt(0) lgkmcnt(0)" ::: "memory");
    __builtin_amdgcn_s_barrier();
    __builtin_amdgcn_sched_barrier(0);
  }

  // ---- epilogue ----
  // lsum: lane l and l^32 cover same q=lane&31 (different kv rows)
  lsum += __shfl_xor(lsum, 32);
  float* lred = (float*)SMEM;
  if (lane < 32) lred[wave * 32 + lane] = lsum;
  __syncthreads();
  float ltot = lsum + lred[(wave ^ 4) * 32 + l31];
  __syncthreads();

  // cross-wh O combine: wh0 sends ct4-7 (region 0), wh1 sends ct0-3 (region 1)
  float* ex = (float*)SMEM;
  if (wh == 0) {
#pragma unroll
    for (int ctl = 0; ctl < 4; ++ctl)
#pragma unroll
      for (int r = 0; r < 16; ++r)
        ex[((wr * 4 + ctl) * 16 + r) * 64 + lane] = acco[4 + ctl][r];
  } else {
#pragma unroll
    for (int ctl = 0; ctl < 4; ++ctl)
#pragma unroll
      for (int r = 0; r < 16; ++r)
        ex[16384 + ((wr * 4 + ctl) * 16 + r) * 64 + lane] = acco[ctl][r];
  }
  __syncthreads();

  float linv[16];
#pragma unroll
  for (int r = 0; r < 16; ++r) {
    int q = (r & 3) + 8 * (r >> 2) + 4 * h;
    linv[r] = 1.f / __shfl(ltot, q);
  }

  unsigned short* ob = ot + (size_t)b * 1024 * 256;
  if (wh == 0) {
#pragma unroll
    for (int ctl = 0; ctl < 4; ++ctl) {
#pragma unroll
      for (int r = 0; r < 16; ++r) {
        float o = (acco[ctl][r] + ex[16384 + ((wr * 4 + ctl) * 16 + r) * 64 + lane]) * linv[r];
        int q = (r & 3) + 8 * (r >> 2) + 4 * h;
        ob[(size_t)(q0 + wr * 32 + q) * 256 + ctl * 32 + l31] = f2bf(o);
      }
    }
  } else {
#pragma unroll
    for (int ctl = 0; ctl < 4; ++ctl) {
#pragma unroll
      for (int r = 0; r < 16; ++r) {
        float o = (acco[4 + ctl][r] + ex[((wr * 4 + ctl) * 16 + r) * 64 + lane]) * linv[r];
        int q = (r & 3) + 8 * (r >> 2) + 4 * h;
        ob[(size_t)(q0 + wr * 32 + q) * 256 + (4 + ctl) * 32 + l31] = f2bf(o);
      }
    }
  }
}

extern "C" void kernel_launch(void* const* d_in, const int* in_sizes, int n_in,
                              void* d_out, int out_size, void* d_ws, size_t ws_size,
                              hipStream_t stream) {
  const float* x    = (const float*)d_in[0];
  const float* gnsc = (const float*)d_in[1];
  const float* gnb  = (const float*)d_in[2];
  const float* wq   = (const float*)d_in[3];
  const float* bq   = (const float*)d_in[4];
  const float* wk   = (const float*)d_in[5];
  const float* bk   = (const float*)d_in[6];
  const float* wv   = (const float*)d_in[7];
  const float* bv   = (const float*)d_in[8];
  const float* wo   = (const float*)d_in[9];
  const float* bo   = (const float*)d_in[10];
  float* out = (float*)d_out;

  unsigned short* wqkb = (unsigned short*)d_ws;          // [512][256]
  unsigned short* wvb  = wqkb + 131072;
  unsigned short* wob  = wvb + 65536;
  float*          bqkf = (float*)(wob + 65536);          // [512] f32
  unsigned short* h    = wob + 65536 + 2048;             // [32][1024][256]
  unsigned short* qkb  = h + 8388608;                    // [32][1024][512]
  unsigned short* vt   = qkb + 16777216;                 // [32][256][1024]
  unsigned short* ot   = h;                              // reuse

  const long long sHN = 1024LL * 256;
  const long long sQK = 1024LL * 512;

  convert_w<<<dim3(64, 4), 256, 0, stream>>>(wq, wk, wv, wo, bq, bk, wqkb, wvb, wob, bqkf);
  gn_kernel<<<dim3(1024), 256, 0, stream>>>(x, gnsc, gnb, h);
  gemm_bt<false, 2, false><<<dim3(4, 8, 32), 256, 0, stream>>>(
      h, sHN, wqkb, 0, qkb, sQK, bqkf, nullptr, 0, 1024, 512, 256, 1.f);
  gemm_bt<false, 1, false><<<dim3(8, 2, 32), 256, 0, stream>>>(
      wvb, 0, h, sHN, vt, sHN, bv, nullptr, 0, 256, 1024, 256, 1.f);
  flash_attn<<<dim3(256), 512, 0, stream>>>(qkb, vt, ot);
  gemm_bt<true, 1, true><<<dim3(8, 2, 32), 256, 0, stream>>>(
      wob, 0, ot, sHN, out, sHN, bo, x, sHN, 256, 1024, 256, 1.f);
}

// Round 9
// 118.734 us; speedup vs baseline: 1.1522x; 1.1507x over previous
//
#include <hip/hip_runtime.h>

typedef __attribute__((ext_vector_type(4))) float f32x4;
typedef __attribute__((ext_vector_type(16))) float f32x16;
typedef __attribute__((ext_vector_type(8))) short bf16x8;

__device__ __forceinline__ unsigned short f2bf(float f) {
  union { float f; unsigned u; } v; v.f = f;
  unsigned r = (v.u + 0x7FFFu + ((v.u >> 16) & 1u)) >> 16;
  return (unsigned short)r;
}

__device__ __forceinline__ unsigned cvt_pk_bf16(float lo, float hi) {
  unsigned r;
  asm("v_cvt_pk_bf16_f32 %0, %1, %2" : "=v"(r) : "v"(lo), "v"(hi));
  return r;
}

__device__ __forceinline__ void load16_lds(const void* g, void* l) {
  __builtin_amdgcn_global_load_lds(
      (__attribute__((address_space(1))) void*)(uintptr_t)g,
      (__attribute__((address_space(3))) void*)(unsigned int)(uintptr_t)l,
      16, 0, 0);
}

// log2(e) / sqrt(256)
#define QSCALE 0.09016844f

// ---------- weight fp32 -> bf16 convert; Wq,bq pre-scaled by QSCALE ----------
__global__ __launch_bounds__(256) void convert_w(
    const float* __restrict__ wq, const float* __restrict__ wk,
    const float* __restrict__ wv, const float* __restrict__ wo,
    const float* __restrict__ bq, const float* __restrict__ bk,
    unsigned short* __restrict__ wqkb, unsigned short* __restrict__ wvb,
    unsigned short* __restrict__ wob, float* __restrict__ bqkf) {
  const float* src[4] = {wq, wk, wv, wo};
  unsigned short* dst[4] = {wqkb, wqkb + 65536, wvb, wob};
  int ti = blockIdx.y;
  float sc = (ti == 0) ? QSCALE : 1.f;
  int idx = blockIdx.x * 256 + threadIdx.x;
  float4 v = ((const float4*)src[ti])[idx];
  ushort4 r;
  r.x = f2bf(v.x * sc); r.y = f2bf(v.y * sc);
  r.z = f2bf(v.z * sc); r.w = f2bf(v.w * sc);
  ((ushort4*)dst[ti])[idx] = r;
  if (ti == 3 && blockIdx.x == 0) {
    bqkf[threadIdx.x] = bq[threadIdx.x] * QSCALE;
    bqkf[256 + threadIdx.x] = bk[threadIdx.x];
  }
}

// ---------- GroupNorm: x[b][c][n] f32 -> h_t[b][n][c] bf16 ----------
__global__ __launch_bounds__(256) void gn_kernel(
    const float* __restrict__ x, const float* __restrict__ gamma,
    const float* __restrict__ beta, unsigned short* __restrict__ h) {
  __shared__ float xs[8 * 1024];
  __shared__ float red[16];
  const int t = threadIdx.x;
  const int b = blockIdx.x >> 5, g = blockIdx.x & 31;
  const float* xp = x + (size_t)(b * 256 + g * 8) * 1024;
  float s = 0.f, ss = 0.f;
#pragma unroll
  for (int j = 0; j < 8; ++j) {
    float4 v = ((const float4*)xp)[j * 256 + t];
    ((float4*)xs)[j * 256 + t] = v;
    s += v.x + v.y + v.z + v.w;
    ss += v.x * v.x + v.y * v.y + v.z * v.z + v.w * v.w;
  }
#pragma unroll
  for (int o = 32; o >= 1; o >>= 1) {
    s += __shfl_xor(s, o);
    ss += __shfl_xor(ss, o);
  }
  const int wave = t >> 6, lane = t & 63;
  if (lane == 0) { red[wave] = s; red[wave + 4] = ss; }
  __syncthreads();
  s = red[0] + red[1] + red[2] + red[3];
  ss = red[4] + red[5] + red[6] + red[7];
  float mean = s * (1.f / 8192.f);
  float var = ss * (1.f / 8192.f) - mean * mean;
  float rstd = rsqrtf(var + 1e-5f);
  float a[8], c[8];
#pragma unroll
  for (int ci = 0; ci < 8; ++ci) {
    float gm = gamma[g * 8 + ci], bt = beta[g * 8 + ci];
    a[ci] = rstd * gm;
    c[ci] = bt - mean * rstd * gm;
  }
  unsigned short* hb = h + (size_t)b * 1024 * 256 + g * 8;
#pragma unroll
  for (int j = 0; j < 4; ++j) {
    int n = j * 256 + t;
    float f0 = xs[0 * 1024 + n] * a[0] + c[0];
    float f1 = xs[1 * 1024 + n] * a[1] + c[1];
    float f2 = xs[2 * 1024 + n] * a[2] + c[2];
    float f3 = xs[3 * 1024 + n] * a[3] + c[3];
    float f4 = xs[4 * 1024 + n] * a[4] + c[4];
    float f5 = xs[5 * 1024 + n] * a[5] + c[5];
    float f6 = xs[6 * 1024 + n] * a[6] + c[6];
    float f7 = xs[7 * 1024 + n] * a[7] + c[7];
    uint4 o4;
    o4.x = (unsigned)f2bf(f0) | ((unsigned)f2bf(f1) << 16);
    o4.y = (unsigned)f2bf(f2) | ((unsigned)f2bf(f3) << 16);
    o4.z = (unsigned)f2bf(f4) | ((unsigned)f2bf(f5) << 16);
    o4.w = (unsigned)f2bf(f6) | ((unsigned)f2bf(f7) << 16);
    *(uint4*)(hb + (size_t)n * 256) = o4;
  }
}

// ---------- generic MFMA GEMM: C[M][N] = alpha * A[M][K] * B[N][K]^T ----------
template <bool OUT_F32, int BIAS_MODE, bool HAS_RES>
__global__ __launch_bounds__(256) void gemm_bt(
    const unsigned short* __restrict__ A, long long sAb,
    const unsigned short* __restrict__ Bm, long long sBb,
    void* __restrict__ Cv, long long sCb,
    const float* __restrict__ bias,
    const float* __restrict__ res, long long sRb,
    int M, int N, int K, float alpha) {
  __shared__ unsigned short As[128 * 32];
  __shared__ unsigned short Bs[128 * 32];
  const int t = threadIdx.x;
  const int wave = t >> 6, lane = t & 63;
  const int bm = blockIdx.y * 128, bn = blockIdx.x * 128;
  const int bz = blockIdx.z;
  const unsigned short* Ab = A + (size_t)bz * sAb;
  const unsigned short* Bb = Bm + (size_t)bz * sBb;
  const int wm = (wave >> 1) * 64, wn = (wave & 1) * 64;
  const int srow = t >> 2;
  const int schunk = t & 3;
  const int lrow = lane & 15, kg = lane >> 4;

  f32x4 acc[4][4] = {};

  for (int k0 = 0; k0 < K; k0 += 32) {
#pragma unroll
    for (int r = 0; r < 2; ++r) {
      int row = r * 64 + srow;
      int cs = schunk ^ ((row >> 1) & 3);
      const unsigned short* ga = Ab + (size_t)(bm + row) * K + (k0 + cs * 8);
      const unsigned short* gb = Bb + (size_t)(bn + row) * K + (k0 + cs * 8);
      load16_lds(ga, &As[(r * 64 + wave * 16) * 32]);
      load16_lds(gb, &Bs[(r * 64 + wave * 16) * 32]);
    }
    __syncthreads();
    bf16x8 af[4], bfr[4];
#pragma unroll
    for (int i = 0; i < 4; ++i) {
      int ra = wm + i * 16 + lrow;
      af[i] = *(const bf16x8*)&As[ra * 32 + ((kg ^ ((ra >> 1) & 3)) * 8)];
      int rb = wn + i * 16 + lrow;
      bfr[i] = *(const bf16x8*)&Bs[rb * 32 + ((kg ^ ((rb >> 1) & 3)) * 8)];
    }
#pragma unroll
    for (int i = 0; i < 4; ++i)
#pragma unroll
      for (int j = 0; j < 4; ++j)
        acc[i][j] = __builtin_amdgcn_mfma_f32_16x16x32_bf16(af[i], bfr[j], acc[i][j], 0, 0, 0);
    __syncthreads();
  }

#pragma unroll
  for (int i = 0; i < 4; ++i) {
#pragma unroll
    for (int j = 0; j < 4; ++j) {
#pragma unroll
      for (int r = 0; r < 4; ++r) {
        int m = bm + wm + i * 16 + (lane >> 4) * 4 + r;
        int n = bn + wn + j * 16 + lrow;
        float v = acc[i][j][r] * alpha;
        if constexpr (BIAS_MODE == 1) v += bias[m];
        if constexpr (BIAS_MODE == 2) v += bias[n];
        if constexpr (HAS_RES) v += res[(size_t)bz * sRb + (size_t)m * N + n];
        if constexpr (OUT_F32)
          ((float*)Cv)[(size_t)bz * sCb + (size_t)m * N + n] = v;
        else
          ((unsigned short*)Cv)[(size_t)bz * sCb + (size_t)m * N + n] = f2bf(v);
      }
    }
  }
}

// ---------- fused flash attention v5 ----------
// v3 skeleton (single barrier/tile, P via LDS, 16x16 PV, acc 64 regs) +
// swapped 32x32 QK (lane-local lsum) + packed b64 P-writes + raw v_exp.
// qk: [32][1024][512] (q cols 0-255 pre-scaled by QSCALE*log2e, k cols 256-511)
// vt: [32][256][1024]; ot: [32][1024][256].
// 8 waves: QK decomp = (wr=wave>>1 q-group) x (wh=wave&1 kv-half);
//          PV decomp = (wr q-group) x (wc=wave&1 col-half).
__global__ __launch_bounds__(512, 2) void flash_attn(
    const unsigned short* __restrict__ qk,
    const unsigned short* __restrict__ vt,
    unsigned short* __restrict__ ot) {
  // 160 KiB exactly: K 2x32KB | V 2x32KB | P 2x16KB
  __shared__ unsigned short SMEM[81920];
  const int VS = 32768, PB = 65536;

  const int t = threadIdx.x;
  const int wave = t >> 6, lane = t & 63;
  const int wr = wave >> 1, wh = wave & 1;
  const int lrow = lane & 15, hi = lane >> 4;
  const int l31 = lane & 31, h2 = lane >> 5;

  const int lbid = blockIdx.x;
  const int logical = (lbid & 7) * 32 + (lbid >> 3);
  const int b = logical >> 3;
  const int q0 = (logical & 7) * 128;

  const unsigned short* qb = qk + (size_t)b * 1024 * 512;
  const unsigned short* kb = qb + 256;
  const unsigned short* vb = vt + (size_t)b * 1024 * 256;

  // ---- prologue: stage K(0) into Ks[0] ----
#pragma unroll
  for (int p = 0; p < 4; ++p) {
    int row = p * 16 + wave * 2 + (lane >> 5);
    int ch = l31 ^ (row & 31);
    load16_lds(kb + (size_t)row * 512 + ch * 8, &SMEM[(p * 16 + wave * 2) * 256]);
  }

  // ---- Q resident: B-fragments for swapped 32x32 QK (q = wr*32 + l31) ----
  bf16x8 aq[16];
#pragma unroll
  for (int kk = 0; kk < 16; ++kk)
    aq[kk] = *(const bf16x8*)(qb + (size_t)(q0 + wr * 32 + l31) * 512 + kk * 16 + h2 * 8);

  f32x4 acco[2][8] = {};
  float lsum = 0.f;

  asm volatile("s_waitcnt vmcnt(0)" ::: "memory");
  __builtin_amdgcn_s_barrier();
  __builtin_amdgcn_sched_barrier(0);

  for (int tt = 0; tt <= 16; ++tt) {
    const int cur = tt & 1, nxt = cur ^ 1;

    // ---- stage K(tt+1) -> Ks[nxt] ----
    if (tt < 15) {
      const unsigned short* kn = kb + (size_t)(tt + 1) * 64 * 512;
#pragma unroll
      for (int p = 0; p < 4; ++p) {
        int row = p * 16 + wave * 2 + (lane >> 5);
        int ch = l31 ^ (row & 31);
        load16_lds(kn + (size_t)row * 512 + ch * 8, &SMEM[nxt * 16384 + (p * 16 + wave * 2) * 256]);
      }
    }
    // ---- stage V(tt) -> Vs[cur] ----
    if (tt < 16) {
      const unsigned short* vn = vb + tt * 64;
#pragma unroll
      for (int p = 0; p < 4; ++p) {
        int row = p * 64 + wave * 8 + (lane >> 3);
        int ch = (lane & 7) ^ (row & 7);
        load16_lds(vn + (size_t)row * 1024 + ch * 8, &SMEM[VS + cur * 16384 + (p * 64 + wave * 8) * 64]);
      }
    }

    // ---- QK(tt): S^T = K . Q^T (swapped 32x32). col=lane&31=q, rows=kv ----
    f32x16 accs = {};
    if (tt < 16) {
      const int kbase = cur * 16384;
      const int krow = (wh * 32 + l31) * 256;
      __builtin_amdgcn_s_setprio(1);
#pragma unroll
      for (int kk = 0; kk < 16; ++kk) {
        bf16x8 kf = *(const bf16x8*)&SMEM[kbase + krow + (((kk * 2 + h2) ^ l31) << 3)];
        accs = __builtin_amdgcn_mfma_f32_32x32x16_bf16(kf, aq[kk], accs, 0, 0, 0);
      }
      __builtin_amdgcn_s_setprio(0);
    }

    // ---- PV(tt-1) from Pb[nxt], Vs[nxt] (16x16, v3-verified) ----
    if (tt >= 1) {
      const unsigned short* Pp = &SMEM[PB + nxt * 8192];
      const unsigned short* Vp = &SMEM[VS + nxt * 16384];
#pragma unroll
      for (int kk2 = 0; kk2 < 2; ++kk2) {
        int qa0 = wr * 32 + lrow;
        int qa1 = qa0 + 16;
        bf16x8 pa0 = *(const bf16x8*)&Pp[qa0 * 64 + ((kk2 * 32 + hi * 8) ^ ((qa0 & 7) << 3))];
        bf16x8 pa1 = *(const bf16x8*)&Pp[qa1 * 64 + ((kk2 * 32 + hi * 8) ^ ((qa1 & 7) << 3))];
        __builtin_amdgcn_s_setprio(1);
#pragma unroll
        for (int jj = 0; jj < 8; ++jj) {
          int c = wh * 128 + jj * 16 + lrow;  // wh doubles as wc here
          bf16x8 bv8 = *(const bf16x8*)&Vp[c * 64 + (((kk2 * 4 + hi) ^ (c & 7)) * 8)];
          acco[0][jj] = __builtin_amdgcn_mfma_f32_16x16x32_bf16(pa0, bv8, acco[0][jj], 0, 0, 0);
          acco[1][jj] = __builtin_amdgcn_mfma_f32_16x16x32_bf16(pa1, bv8, acco[1][jj], 0, 0, 0);
        }
        __builtin_amdgcn_s_setprio(0);
      }
    }

    // ---- exp(tt): P = exp2(S) -> Pb[cur] via cvt_pk + ds_write_b64 ----
    if (tt < 16) {
      char* Pw = (char*)&SMEM[PB + cur * 8192];
      const int q = wr * 32 + l31;
      const int qoff = q * 128 + (h2 << 3);
      const int qx = (q & 7);
#pragma unroll
      for (int m = 0; m < 4; ++m) {
        float e0 = __builtin_amdgcn_exp2f(accs[4 * m + 0]);
        float e1 = __builtin_amdgcn_exp2f(accs[4 * m + 1]);
        float e2 = __builtin_amdgcn_exp2f(accs[4 * m + 2]);
        float e3 = __builtin_amdgcn_exp2f(accs[4 * m + 3]);
        lsum += (e0 + e1) + (e2 + e3);
        uint2 w2;
        w2.x = cvt_pk_bf16(e0, e1);
        w2.y = cvt_pk_bf16(e2, e3);
        int c = wh * 4 + m;
        *(uint2*)(Pw + qoff + ((c ^ qx) << 4)) = w2;
      }
    }

    // ---- single end-of-interval barrier ----
    asm volatile("s_waitcnt vmcnt(0) lgkmcnt(0)" ::: "memory");
    __builtin_amdgcn_s_barrier();
    __builtin_amdgcn_sched_barrier(0);
  }

  // ---- epilogue ----
  // lane l and l^32 hold same q (different kv subsets)
  lsum += __shfl_xor(lsum, 32);
  float* lred = (float*)SMEM;  // Ks region dead
  if (lane < 32) lred[wave * 32 + lane] = lsum;
  __syncthreads();

  unsigned short* ob = ot + (size_t)b * 1024 * 256;
#pragma unroll
  for (int i = 0; i < 2; ++i) {
    float inv[4];
#pragma unroll
    for (int r = 0; r < 4; ++r) {
      int rl = wr * 32 + i * 16 + hi * 4 + r;
      inv[r] = 1.f / (lred[wr * 64 + (rl & 31)] + lred[wr * 64 + 32 + (rl & 31)]);
    }
#pragma unroll
    for (int jj = 0; jj < 8; ++jj)
#pragma unroll
      for (int r = 0; r < 4; ++r) {
        int n = q0 + wr * 32 + i * 16 + hi * 4 + r;
        int c = wh * 128 + jj * 16 + lrow;
        ob[(size_t)n * 256 + c] = f2bf(acco[i][jj][r] * inv[r]);
      }
  }
}

extern "C" void kernel_launch(void* const* d_in, const int* in_sizes, int n_in,
                              void* d_out, int out_size, void* d_ws, size_t ws_size,
                              hipStream_t stream) {
  const float* x    = (const float*)d_in[0];
  const float* gnsc = (const float*)d_in[1];
  const float* gnb  = (const float*)d_in[2];
  const float* wq   = (const float*)d_in[3];
  const float* bq   = (const float*)d_in[4];
  const float* wk   = (const float*)d_in[5];
  const float* bk   = (const float*)d_in[6];
  const float* wv   = (const float*)d_in[7];
  const float* bv   = (const float*)d_in[8];
  const float* wo   = (const float*)d_in[9];
  const float* bo   = (const float*)d_in[10];
  float* out = (float*)d_out;

  unsigned short* wqkb = (unsigned short*)d_ws;          // [512][256]
  unsigned short* wvb  = wqkb + 131072;
  unsigned short* wob  = wvb + 65536;
  float*          bqkf = (float*)(wob + 65536);          // [512] f32
  unsigned short* h    = wob + 65536 + 2048;             // [32][1024][256]
  unsigned short* qkb  = h + 8388608;                    // [32][1024][512]
  unsigned short* vt   = qkb + 16777216;                 // [32][256][1024]
  unsigned short* ot   = h;                              // reuse

  const long long sHN = 1024LL * 256;
  const long long sQK = 1024LL * 512;

  convert_w<<<dim3(64, 4), 256, 0, stream>>>(wq, wk, wv, wo, bq, bk, wqkb, wvb, wob, bqkf);
  gn_kernel<<<dim3(1024), 256, 0, stream>>>(x, gnsc, gnb, h);
  gemm_bt<false, 2, false><<<dim3(4, 8, 32), 256, 0, stream>>>(
      h, sHN, wqkb, 0, qkb, sQK, bqkf, nullptr, 0, 1024, 512, 256, 1.f);
  gemm_bt<false, 1, false><<<dim3(8, 2, 32), 256, 0, stream>>>(
      wvb, 0, h, sHN, vt, sHN, bv, nullptr, 0, 256, 1024, 256, 1.f);
  flash_attn<<<dim3(256), 512, 0, stream>>>(qkb, vt, ot);
  gemm_bt<true, 1, true><<<dim3(8, 2, 32), 256, 0, stream>>>(
      wob, 0, ot, sHN, out, sHN, bo, x, sHN, 256, 1024, 256, 1.f);
}

// Round 10
// 118.246 us; speedup vs baseline: 1.1570x; 1.0041x over previous
//
#include <hip/hip_runtime.h>

typedef __attribute__((ext_vector_type(4))) float f32x4;
typedef __attribute__((ext_vector_type(16))) float f32x16;
typedef __attribute__((ext_vector_type(8))) short bf16x8;

__device__ __forceinline__ unsigned short f2bf(float f) {
  union { float f; unsigned u; } v; v.f = f;
  unsigned r = (v.u + 0x7FFFu + ((v.u >> 16) & 1u)) >> 16;
  return (unsigned short)r;
}

__device__ __forceinline__ unsigned cvt_pk_bf16(float lo, float hi) {
  unsigned r;
  asm("v_cvt_pk_bf16_f32 %0, %1, %2" : "=v"(r) : "v"(lo), "v"(hi));
  return r;
}

__device__ __forceinline__ void load16_lds(const void* g, void* l) {
  __builtin_amdgcn_global_load_lds(
      (__attribute__((address_space(1))) void*)(uintptr_t)g,
      (__attribute__((address_space(3))) void*)(unsigned int)(uintptr_t)l,
      16, 0, 0);
}

// log2(e) / sqrt(256)
#define QSCALE 0.09016844f

// ---------- GroupNorm (blocks 0-1023) + weight convert (blocks 1024-1039) ----------
__global__ __launch_bounds__(256) void gn_conv_kernel(
    const float* __restrict__ x, const float* __restrict__ gamma,
    const float* __restrict__ beta, unsigned short* __restrict__ h,
    const float* __restrict__ wq, const float* __restrict__ wk,
    const float* __restrict__ wv, const float* __restrict__ wo,
    const float* __restrict__ bq, const float* __restrict__ bk,
    unsigned short* __restrict__ wqkb, unsigned short* __restrict__ wvb,
    unsigned short* __restrict__ wob, float* __restrict__ bqkf) {
  __shared__ float xs[8 * 1024];
  __shared__ float red[16];
  const int t = threadIdx.x;

  if (blockIdx.x >= 1024) {
    const int wblk = blockIdx.x - 1024;
    const float* src[4] = {wq, wk, wv, wo};
    unsigned short* dst[4] = {wqkb, wqkb + 65536, wvb, wob};
    const int ti = wblk >> 2, part = wblk & 3;
    const float sc = (ti == 0) ? QSCALE : 1.f;
    const float* s = src[ti];
    unsigned short* d = dst[ti];
#pragma unroll
    for (int j = 0; j < 16; ++j) {
      int idx = part * 4096 + j * 256 + t;
      float4 v = ((const float4*)s)[idx];
      ushort4 r;
      r.x = f2bf(v.x * sc); r.y = f2bf(v.y * sc);
      r.z = f2bf(v.z * sc); r.w = f2bf(v.w * sc);
      ((ushort4*)d)[idx] = r;
    }
    if (wblk == 0) {
      bqkf[t] = bq[t] * QSCALE;
      bqkf[256 + t] = bk[t];
    }
    return;
  }

  const int b = blockIdx.x >> 5, g = blockIdx.x & 31;
  const float* xp = x + (size_t)(b * 256 + g * 8) * 1024;
  float s = 0.f, ss = 0.f;
#pragma unroll
  for (int j = 0; j < 8; ++j) {
    float4 v = ((const float4*)xp)[j * 256 + t];
    ((float4*)xs)[j * 256 + t] = v;
    s += v.x + v.y + v.z + v.w;
    ss += v.x * v.x + v.y * v.y + v.z * v.z + v.w * v.w;
  }
#pragma unroll
  for (int o = 32; o >= 1; o >>= 1) {
    s += __shfl_xor(s, o);
    ss += __shfl_xor(ss, o);
  }
  const int wave = t >> 6, lane = t & 63;
  if (lane == 0) { red[wave] = s; red[wave + 4] = ss; }
  __syncthreads();
  s = red[0] + red[1] + red[2] + red[3];
  ss = red[4] + red[5] + red[6] + red[7];
  float mean = s * (1.f / 8192.f);
  float var = ss * (1.f / 8192.f) - mean * mean;
  float rstd = rsqrtf(var + 1e-5f);
  float a[8], c[8];
#pragma unroll
  for (int ci = 0; ci < 8; ++ci) {
    float gm = gamma[g * 8 + ci], bt = beta[g * 8 + ci];
    a[ci] = rstd * gm;
    c[ci] = bt - mean * rstd * gm;
  }
  unsigned short* hb = h + (size_t)b * 1024 * 256 + g * 8;
#pragma unroll
  for (int j = 0; j < 4; ++j) {
    int n = j * 256 + t;
    float f0 = xs[0 * 1024 + n] * a[0] + c[0];
    float f1 = xs[1 * 1024 + n] * a[1] + c[1];
    float f2 = xs[2 * 1024 + n] * a[2] + c[2];
    float f3 = xs[3 * 1024 + n] * a[3] + c[3];
    float f4 = xs[4 * 1024 + n] * a[4] + c[4];
    float f5 = xs[5 * 1024 + n] * a[5] + c[5];
    float f6 = xs[6 * 1024 + n] * a[6] + c[6];
    float f7 = xs[7 * 1024 + n] * a[7] + c[7];
    uint4 o4;
    o4.x = (unsigned)f2bf(f0) | ((unsigned)f2bf(f1) << 16);
    o4.y = (unsigned)f2bf(f2) | ((unsigned)f2bf(f3) << 16);
    o4.z = (unsigned)f2bf(f4) | ((unsigned)f2bf(f5) << 16);
    o4.w = (unsigned)f2bf(f6) | ((unsigned)f2bf(f7) << 16);
    *(uint4*)(hb + (size_t)n * 256) = o4;
  }
}

// ---------- single-barrier dbuf MFMA GEMM core: C[M][N] = A[M][K]*B[N][K]^T ----------
// bias_mode: 1 row (bias[m]), 2 col (bias[n]). LDS: As/Bs 2 bufs x 128x32 each.
template <bool OUT_F32, bool HAS_RES>
__device__ __forceinline__ void gemm_core(
    const unsigned short* __restrict__ Ab, const unsigned short* __restrict__ Bb,
    void* __restrict__ Cb, const float* __restrict__ bias, int bias_mode,
    const float* __restrict__ res, int bm, int bn, int N, int K,
    unsigned short* As, unsigned short* Bs) {
  const int t = threadIdx.x;
  const int wave = t >> 6, lane = t & 63;
  const int wm = (wave >> 1) * 64, wn = (wave & 1) * 64;
  const int srow = t >> 2, schunk = t & 3;
  const int lrow = lane & 15, kg = lane >> 4;

  f32x4 acc[4][4] = {};

  // prologue: stage k-step 0 into buf 0
#pragma unroll
  for (int r = 0; r < 2; ++r) {
    int row = r * 64 + srow;
    int cs = schunk ^ ((row >> 1) & 3);
    load16_lds(Ab + (size_t)(bm + row) * K + cs * 8, &As[(r * 64 + wave * 16) * 32]);
    load16_lds(Bb + (size_t)(bn + row) * K + cs * 8, &Bs[(r * 64 + wave * 16) * 32]);
  }
  asm volatile("s_waitcnt vmcnt(0)" ::: "memory");
  __builtin_amdgcn_s_barrier();
  __builtin_amdgcn_sched_barrier(0);

  const int nk = K >> 5;
  for (int kt = 0; kt < nk; ++kt) {
    const int cur = kt & 1;
    // issue stage of k-step kt+1 into buf cur^1 (drained at end-of-iter barrier)
    if (kt + 1 < nk) {
      const int k0 = (kt + 1) << 5;
      const int boff = (cur ^ 1) * 4096;
#pragma unroll
      for (int r = 0; r < 2; ++r) {
        int row = r * 64 + srow;
        int cs = schunk ^ ((row >> 1) & 3);
        load16_lds(Ab + (size_t)(bm + row) * K + (k0 + cs * 8), &As[boff + (r * 64 + wave * 16) * 32]);
        load16_lds(Bb + (size_t)(bn + row) * K + (k0 + cs * 8), &Bs[boff + (r * 64 + wave * 16) * 32]);
      }
    }
    const int boff = cur * 4096;
    bf16x8 af[4], bfr[4];
#pragma unroll
    for (int i = 0; i < 4; ++i) {
      int ra = wm + i * 16 + lrow;
      af[i] = *(const bf16x8*)&As[boff + ra * 32 + ((kg ^ ((ra >> 1) & 3)) * 8)];
      int rb = wn + i * 16 + lrow;
      bfr[i] = *(const bf16x8*)&Bs[boff + rb * 32 + ((kg ^ ((rb >> 1) & 3)) * 8)];
    }
    __builtin_amdgcn_s_setprio(1);
#pragma unroll
    for (int i = 0; i < 4; ++i)
#pragma unroll
      for (int j = 0; j < 4; ++j)
        acc[i][j] = __builtin_amdgcn_mfma_f32_16x16x32_bf16(af[i], bfr[j], acc[i][j], 0, 0, 0);
    __builtin_amdgcn_s_setprio(0);
    asm volatile("s_waitcnt vmcnt(0) lgkmcnt(0)" ::: "memory");
    __builtin_amdgcn_s_barrier();
    __builtin_amdgcn_sched_barrier(0);
  }

#pragma unroll
  for (int i = 0; i < 4; ++i) {
#pragma unroll
    for (int j = 0; j < 4; ++j) {
#pragma unroll
      for (int r = 0; r < 4; ++r) {
        int m = bm + wm + i * 16 + kg * 4 + r;
        int n = bn + wn + j * 16 + lrow;
        float v = acc[i][j][r];
        v += (bias_mode == 1) ? bias[m] : bias[n];
        if constexpr (HAS_RES) v += res[(size_t)m * N + n];
        if constexpr (OUT_F32)
          ((float*)Cb)[(size_t)m * N + n] = v;
        else
          ((unsigned short*)Cb)[(size_t)m * N + n] = f2bf(v);
      }
    }
  }
}

// ---------- merged projection launch: qk-GEMM (tiles 0-31) + v-GEMM (tiles 32-47) ----------
__global__ __launch_bounds__(256) void proj_kernel(
    const unsigned short* __restrict__ h, const unsigned short* __restrict__ wqkb,
    const unsigned short* __restrict__ wvb, unsigned short* __restrict__ qkb,
    unsigned short* __restrict__ vtb, const float* __restrict__ bqkf,
    const float* __restrict__ bv) {
  __shared__ unsigned short As[2 * 4096];
  __shared__ unsigned short Bs[2 * 4096];
  const int tid = blockIdx.x;
  const int bz = blockIdx.y;
  const long long sHN = 1024LL * 256, sQK = 1024LL * 512;
  if (tid < 32) {
    // qk: M=1024 (n rows from h), N=512 (q|k out), col bias
    int bn = (tid & 3) * 128, bm = (tid >> 2) * 128;
    gemm_core<false, false>(h + bz * sHN, wqkb, qkb + bz * sQK,
                            bqkf, 2, nullptr, bm, bn, 512, 256, As, Bs);
  } else {
    // v: M=256 (c rows from Wv), N=1024 (m), row bias
    int t2 = tid - 32;
    int bn = (t2 & 7) * 128, bm = (t2 >> 3) * 128;
    gemm_core<false, false>(wvb, h + bz * sHN, vtb + bz * sHN,
                            bv, 1, nullptr, bm, bn, 1024, 256, As, Bs);
  }
}

// ---------- out-projection + residual ----------
__global__ __launch_bounds__(256) void out_kernel(
    const unsigned short* __restrict__ wob, const unsigned short* __restrict__ ot,
    float* __restrict__ out, const float* __restrict__ bo,
    const float* __restrict__ x) {
  __shared__ unsigned short As[2 * 4096];
  __shared__ unsigned short Bs[2 * 4096];
  const int tid = blockIdx.x;
  const int bz = blockIdx.y;
  const long long sHN = 1024LL * 256;
  int bn = (tid & 7) * 128, bm = (tid >> 3) * 128;
  gemm_core<true, true>(wob, ot + bz * sHN, out + bz * sHN,
                        bo, 1, x + bz * sHN, bm, bn, 1024, 256, As, Bs);
}

// ---------- fused flash attention v5.1 (P chunk-rotation swizzle) ----------
// qk: [32][1024][512] (q cols 0-255 pre-scaled, k cols 256-511)
// vt: [32][256][1024]; ot: [32][1024][256].
__global__ __launch_bounds__(512, 2) void flash_attn(
    const unsigned short* __restrict__ qk,
    const unsigned short* __restrict__ vt,
    unsigned short* __restrict__ ot) {
  __shared__ unsigned short SMEM[81920];
  const int VS = 32768, PB = 65536;

  const int t = threadIdx.x;
  const int wave = t >> 6, lane = t & 63;
  const int wr = wave >> 1, wh = wave & 1;
  const int lrow = lane & 15, hi = lane >> 4;
  const int l31 = lane & 31, h2 = lane >> 5;

  const int lbid = blockIdx.x;
  const int logical = (lbid & 7) * 32 + (lbid >> 3);
  const int b = logical >> 3;
  const int q0 = (logical & 7) * 128;

  const unsigned short* qb = qk + (size_t)b * 1024 * 512;
  const unsigned short* kb = qb + 256;
  const unsigned short* vb = vt + (size_t)b * 1024 * 256;

#pragma unroll
  for (int p = 0; p < 4; ++p) {
    int row = p * 16 + wave * 2 + (lane >> 5);
    int ch = l31 ^ (row & 31);
    load16_lds(kb + (size_t)row * 512 + ch * 8, &SMEM[(p * 16 + wave * 2) * 256]);
  }

  bf16x8 aq[16];
#pragma unroll
  for (int kk = 0; kk < 16; ++kk)
    aq[kk] = *(const bf16x8*)(qb + (size_t)(q0 + wr * 32 + l31) * 512 + kk * 16 + h2 * 8);

  f32x4 acco[2][8] = {};
  float lsum = 0.f;

  asm volatile("s_waitcnt vmcnt(0)" ::: "memory");
  __builtin_amdgcn_s_barrier();
  __builtin_amdgcn_sched_barrier(0);

  for (int tt = 0; tt <= 16; ++tt) {
    const int cur = tt & 1, nxt = cur ^ 1;

    if (tt < 15) {
      const unsigned short* kn = kb + (size_t)(tt + 1) * 64 * 512;
#pragma unroll
      for (int p = 0; p < 4; ++p) {
        int row = p * 16 + wave * 2 + (lane >> 5);
        int ch = l31 ^ (row & 31);
        load16_lds(kn + (size_t)row * 512 + ch * 8, &SMEM[nxt * 16384 + (p * 16 + wave * 2) * 256]);
      }
    }
    if (tt < 16) {
      const unsigned short* vn = vb + tt * 64;
#pragma unroll
      for (int p = 0; p < 4; ++p) {
        int row = p * 64 + wave * 8 + (lane >> 3);
        int ch = (lane & 7) ^ (row & 7);
        load16_lds(vn + (size_t)row * 1024 + ch * 8, &SMEM[VS + cur * 16384 + (p * 64 + wave * 8) * 64]);
      }
    }

    // QK(tt): S^T = K . Q^T (swapped 32x32)
    f32x16 accs = {};
    if (tt < 16) {
      const int kbase = cur * 16384;
      const int krow = (wh * 32 + l31) * 256;
      __builtin_amdgcn_s_setprio(1);
#pragma unroll
      for (int kk = 0; kk < 16; ++kk) {
        bf16x8 kf = *(const bf16x8*)&SMEM[kbase + krow + (((kk * 2 + h2) ^ l31) << 3)];
        accs = __builtin_amdgcn_mfma_f32_32x32x16_bf16(kf, aq[kk], accs, 0, 0, 0);
      }
      __builtin_amdgcn_s_setprio(0);
    }

    // PV(tt-1) from Pb[nxt], Vs[nxt]
    if (tt >= 1) {
      const unsigned short* Pp = &SMEM[PB + nxt * 8192];
      const unsigned short* Vp = &SMEM[VS + nxt * 16384];
      const int qa0 = wr * 32 + lrow;
      const int qa1 = qa0 + 16;
      const int rot0 = (lrow >> 3) & 3;
      const int rot1 = (rot0 + 2) & 3;
#pragma unroll
      for (int kk2 = 0; kk2 < 2; ++kk2) {
        bf16x8 pa0 = *(const bf16x8*)&Pp[qa0 * 64 + ((((kk2 * 4 + hi + 2 * rot0) & 7) ^ (qa0 & 7)) << 3)];
        bf16x8 pa1 = *(const bf16x8*)&Pp[qa1 * 64 + ((((kk2 * 4 + hi + 2 * rot1) & 7) ^ (qa1 & 7)) << 3)];
        __builtin_amdgcn_s_setprio(1);
#pragma unroll
        for (int jj = 0; jj < 8; ++jj) {
          int c = wh * 128 + jj * 16 + lrow;
          bf16x8 bv8 = *(const bf16x8*)&Vp[c * 64 + (((kk2 * 4 + hi) ^ (c & 7)) * 8)];
          acco[0][jj] = __builtin_amdgcn_mfma_f32_16x16x32_bf16(pa0, bv8, acco[0][jj], 0, 0, 0);
          acco[1][jj] = __builtin_amdgcn_mfma_f32_16x16x32_bf16(pa1, bv8, acco[1][jj], 0, 0, 0);
        }
        __builtin_amdgcn_s_setprio(0);
      }
    }

    // exp(tt): P -> Pb[cur] via cvt_pk + b64 writes (rotated chunk swizzle)
    if (tt < 16) {
      char* Pw = (char*)&SMEM[PB + cur * 8192];
      const int q = wr * 32 + l31;
      const int qx = q & 7;
      const int rot2 = (l31 >> 3) & 3;
      const int qoff = q * 128 + (h2 << 3);
#pragma unroll
      for (int m = 0; m < 4; ++m) {
        float e0 = __builtin_amdgcn_exp2f(accs[4 * m + 0]);
        float e1 = __builtin_amdgcn_exp2f(accs[4 * m + 1]);
        float e2 = __builtin_amdgcn_exp2f(accs[4 * m + 2]);
        float e3 = __builtin_amdgcn_exp2f(accs[4 * m + 3]);
        lsum += (e0 + e1) + (e2 + e3);
        uint2 w2;
        w2.x = cvt_pk_bf16(e0, e1);
        w2.y = cvt_pk_bf16(e2, e3);
        int physc = ((wh * 4 + m + 2 * rot2) & 7) ^ qx;
        *(uint2*)(Pw + qoff + (physc << 4)) = w2;
      }
    }

    asm volatile("s_waitcnt vmcnt(0) lgkmcnt(0)" ::: "memory");
    __builtin_amdgcn_s_barrier();
    __builtin_amdgcn_sched_barrier(0);
  }

  // ---- epilogue ----
  lsum += __shfl_xor(lsum, 32);
  float* lred = (float*)SMEM;
  if (lane < 32) lred[wave * 32 + lane] = lsum;
  __syncthreads();

  unsigned short* ob = ot + (size_t)b * 1024 * 256;
#pragma unroll
  for (int i = 0; i < 2; ++i) {
    float inv[4];
#pragma unroll
    for (int r = 0; r < 4; ++r) {
      int rl = wr * 32 + i * 16 + hi * 4 + r;
      inv[r] = 1.f / (lred[wr * 64 + (rl & 31)] + lred[wr * 64 + 32 + (rl & 31)]);
    }
#pragma unroll
    for (int jj = 0; jj < 8; ++jj)
#pragma unroll
      for (int r = 0; r < 4; ++r) {
        int n = q0 + wr * 32 + i * 16 + hi * 4 + r;
        int c = wh * 128 + jj * 16 + lrow;
        ob[(size_t)n * 256 + c] = f2bf(acco[i][jj][r] * inv[r]);
      }
  }
}

extern "C" void kernel_launch(void* const* d_in, const int* in_sizes, int n_in,
                              void* d_out, int out_size, void* d_ws, size_t ws_size,
                              hipStream_t stream) {
  const float* x    = (const float*)d_in[0];
  const float* gnsc = (const float*)d_in[1];
  const float* gnb  = (const float*)d_in[2];
  const float* wq   = (const float*)d_in[3];
  const float* bq   = (const float*)d_in[4];
  const float* wk   = (const float*)d_in[5];
  const float* bk   = (const float*)d_in[6];
  const float* wv   = (const float*)d_in[7];
  const float* bv   = (const float*)d_in[8];
  const float* wo   = (const float*)d_in[9];
  const float* bo   = (const float*)d_in[10];
  float* out = (float*)d_out;

  unsigned short* wqkb = (unsigned short*)d_ws;          // [512][256]
  unsigned short* wvb  = wqkb + 131072;
  unsigned short* wob  = wvb + 65536;
  float*          bqkf = (float*)(wob + 65536);          // [512] f32
  unsigned short* h    = wob + 65536 + 2048;             // [32][1024][256]
  unsigned short* qkb  = h + 8388608;                    // [32][1024][512]
  unsigned short* vt   = qkb + 16777216;                 // [32][256][1024]
  unsigned short* ot   = h;                              // reuse (h dead after proj)

  gn_conv_kernel<<<dim3(1040), 256, 0, stream>>>(
      x, gnsc, gnb, h, wq, wk, wv, wo, bq, bk, wqkb, wvb, wob, bqkf);
  proj_kernel<<<dim3(48, 32), 256, 0, stream>>>(h, wqkb, wvb, qkb, vt, bqkf, bv);
  flash_attn<<<dim3(256), 512, 0, stream>>>(qkb, vt, ot);
  out_kernel<<<dim3(16, 32), 256, 0, stream>>>(wob, ot, out, bo, x);
}